// Round 1
// baseline (8349.442 us; speedup 1.0000x reference)
//
#include <hip/hip_runtime.h>
#include <math.h>

#define T_SEQ     2048
#define HIDDEN_D  2048
#define NUM_KH    16
#define NUM_VH    32
#define HEAD_DIM  128
#define K_TOTAL   2048   // 16*128
#define V_TOTAL   4096   // 32*128
#define QKV_TOTAL 8192   // 2*K_TOTAL + V_TOTAL
#define EPS_F     1e-6f

// ---------------------------------------------------------------------------
// Generic fp32 GEMM: C[M,N] = A[M,K] * B[N,K]^T   (both row-major, N-T form)
// 64x64 tile, BK=16, 256 threads, 4x4 microtile, transposed LDS for float4.
// ---------------------------------------------------------------------------
__global__ __launch_bounds__(256) void gemm_nt_64(
    const float* __restrict__ A, const float* __restrict__ B,
    float* __restrict__ C, int M, int N, int K)
{
    __shared__ float As[16][68];   // [k][m], pad 68 keeps 16B alignment
    __shared__ float Bs[16][68];   // [k][n]
    const int tid = threadIdx.x;
    const int m0 = blockIdx.y * 64;
    const int n0 = blockIdx.x * 64;
    const int tm = tid >> 4;        // 0..15
    const int tn = tid & 15;        // 0..15
    const int lr = tid >> 2;        // 0..63 tile row for staging
    const int lc = (tid & 3) * 4;   // 0,4,8,12 k-offset for staging

    float acc[4][4];
#pragma unroll
    for (int i = 0; i < 4; ++i)
#pragma unroll
        for (int j = 0; j < 4; ++j) acc[i][j] = 0.f;

    for (int kt = 0; kt < K; kt += 16) {
        float4 av = *(const float4*)(A + (size_t)(m0 + lr) * K + kt + lc);
        float4 bv = *(const float4*)(B + (size_t)(n0 + lr) * K + kt + lc);
        As[lc + 0][lr] = av.x; As[lc + 1][lr] = av.y;
        As[lc + 2][lr] = av.z; As[lc + 3][lr] = av.w;
        Bs[lc + 0][lr] = bv.x; Bs[lc + 1][lr] = bv.y;
        Bs[lc + 2][lr] = bv.z; Bs[lc + 3][lr] = bv.w;
        __syncthreads();
#pragma unroll
        for (int kk = 0; kk < 16; ++kk) {
            float4 a4 = *(const float4*)&As[kk][tm * 4];
            float4 b4 = *(const float4*)&Bs[kk][tn * 4];
            float a[4] = {a4.x, a4.y, a4.z, a4.w};
            float b[4] = {b4.x, b4.y, b4.z, b4.w};
#pragma unroll
            for (int i = 0; i < 4; ++i)
#pragma unroll
                for (int j = 0; j < 4; ++j)
                    acc[i][j] = fmaf(a[i], b[j], acc[i][j]);
        }
        __syncthreads();
    }
#pragma unroll
    for (int i = 0; i < 4; ++i) {
        float4 o = make_float4(acc[i][0], acc[i][1], acc[i][2], acc[i][3]);
        *(float4*)(C + (size_t)(m0 + tm * 4 + i) * N + n0 + tn * 4) = o;
    }
}

// ---------------------------------------------------------------------------
// a/b projections fused with gating: g = -exp(A_log)*softplus(a+dt_bias),
// beta = sigmoid(b).  One wave per time step; 32 heads each.
// ---------------------------------------------------------------------------
__global__ __launch_bounds__(64) void gating_kernel(
    const float* __restrict__ hs, const float* __restrict__ Wa,
    const float* __restrict__ Wb, const float* __restrict__ A_log,
    const float* __restrict__ dt_bias, float* __restrict__ g,
    float* __restrict__ beta)
{
    const int t = blockIdx.x;
    const int lane = threadIdx.x;
    const float* x = hs + (size_t)t * HIDDEN_D;
    for (int h = 0; h < NUM_VH; ++h) {
        const float* wa = Wa + (size_t)h * HIDDEN_D;
        const float* wb = Wb + (size_t)h * HIDDEN_D;
        float sa = 0.f, sb = 0.f;
        for (int i = lane; i < HIDDEN_D; i += 64) {
            float xv = x[i];
            sa = fmaf(xv, wa[i], sa);
            sb = fmaf(xv, wb[i], sb);
        }
        for (int off = 32; off > 0; off >>= 1) {
            sa += __shfl_down(sa, off);
            sb += __shfl_down(sb, off);
        }
        if (lane == 0) {
            float aa = sa + dt_bias[h];
            float sp = (aa > 20.f) ? aa : log1pf(expf(aa));
            g[t * NUM_VH + h] = -expf(A_log[h]) * sp;
            beta[t * NUM_VH + h] = 1.f / (1.f + expf(-sb));
        }
    }
}

// ---------------------------------------------------------------------------
// Depthwise causal conv1d (K=4) + SiLU.  y[t,c] = sum_j x[t-3+j,c]*w[c,j]
// ---------------------------------------------------------------------------
__global__ __launch_bounds__(256) void conv_silu_kernel(
    const float* __restrict__ mixed, const float* __restrict__ cw,
    float* __restrict__ qkv)
{
    int idx = blockIdx.x * 256 + threadIdx.x;
    int c = idx & (QKV_TOTAL - 1);
    int t = idx >> 13;               // / QKV_TOTAL
    const float4 w = *(const float4*)(cw + (size_t)c * 4);
    float y = w.w * mixed[(size_t)t * QKV_TOTAL + c];
    if (t >= 1) y = fmaf(w.z, mixed[(size_t)(t - 1) * QKV_TOTAL + c], y);
    if (t >= 2) y = fmaf(w.y, mixed[(size_t)(t - 2) * QKV_TOTAL + c], y);
    if (t >= 3) y = fmaf(w.x, mixed[(size_t)(t - 3) * QKV_TOTAL + c], y);
    qkv[(size_t)t * QKV_TOTAL + c] = y / (1.f + expf(-y));
}

// ---------------------------------------------------------------------------
// L2-normalize q and k head rows in-place (channels 0..4095 of qkv).
// One wave per (t, head-row).
// ---------------------------------------------------------------------------
__global__ __launch_bounds__(64) void l2norm_kernel(float* __restrict__ qkv)
{
    const int row = blockIdx.x;       // t*32 + r
    const int t = row >> 5;
    const int r = row & 31;           // r<16: q head r; r>=16: k head r-16
    float* p = qkv + (size_t)t * QKV_TOTAL + r * HEAD_DIM;
    const int lane = threadIdx.x;
    float2 v = *(float2*)(p + lane * 2);
    float s = v.x * v.x + v.y * v.y;
    for (int off = 32; off > 0; off >>= 1) s += __shfl_down(s, off);
    s = __shfl(s, 0);
    float inv = rsqrtf(s + EPS_F);
    v.x *= inv; v.y *= inv;
    *(float2*)(p + lane * 2) = v;
}

// ---------------------------------------------------------------------------
// Gated delta-rule recurrence.  State column S[:,v] is independent per
// (head, v) -> one lane per v, 64 blocks = (head, v-half), state in VGPRs.
// ---------------------------------------------------------------------------
#define CH 8
__global__ __launch_bounds__(64) void recurrence_kernel(
    const float* __restrict__ qkv, const float* __restrict__ g,
    const float* __restrict__ beta, float* __restrict__ o)
{
    __shared__ float qs[CH][HEAD_DIM];
    __shared__ float ks[CH][HEAD_DIM];
    const int b = blockIdx.x;
    const int h = b >> 1;
    const int half = b & 1;
    const int lane = threadIdx.x;
    const int vv = half * 64 + lane;
    const int kh = h >> 1;            // GQA: v-head h uses k-head h/2
    const float scale = 0.08838834764831845f;  // 128^-0.5

    float4 S[32];
#pragma unroll
    for (int i = 0; i < 32; ++i) S[i] = make_float4(0.f, 0.f, 0.f, 0.f);

    for (int t0 = 0; t0 < T_SEQ; t0 += CH) {
        __syncthreads();
        for (int i = 0; i < CH; ++i) {
            const float* qrow = qkv + (size_t)(t0 + i) * QKV_TOTAL + kh * HEAD_DIM;
            const float* krow = qrow + K_TOTAL;
            qs[i][lane]      = qrow[lane];
            qs[i][lane + 64] = qrow[lane + 64];
            ks[i][lane]      = krow[lane];
            ks[i][lane + 64] = krow[lane + 64];
        }
        __syncthreads();
        for (int i = 0; i < CH; ++i) {
            const int t = t0 + i;
            const float gv = g[t * NUM_VH + h];
            const float bv = beta[t * NUM_VH + h];
            const float eg = expf(gv);
            const float vt = qkv[(size_t)t * QKV_TOTAL + 2 * K_TOTAL
                                 + h * HEAD_DIM + vv];
            // pass 1: pred = eg * (k . S_old)
            float d0 = 0.f, d1 = 0.f, d2 = 0.f, d3 = 0.f;
#pragma unroll
            for (int kk = 0; kk < 32; ++kk) {
                float4 k4 = *(const float4*)&ks[i][kk * 4];
                d0 = fmaf(k4.x, S[kk].x, d0);
                d1 = fmaf(k4.y, S[kk].y, d1);
                d2 = fmaf(k4.z, S[kk].z, d2);
                d3 = fmaf(k4.w, S[kk].w, d3);
            }
            const float pred = eg * (d0 + d1 + d2 + d3);
            const float delta = bv * (vt - pred);
            // pass 2: S = eg*S + k*delta ; o = q . S_new
            float o0 = 0.f, o1 = 0.f, o2 = 0.f, o3 = 0.f;
#pragma unroll
            for (int kk = 0; kk < 32; ++kk) {
                float4 k4 = *(const float4*)&ks[i][kk * 4];
                float4 q4 = *(const float4*)&qs[i][kk * 4];
                S[kk].x = fmaf(eg, S[kk].x, k4.x * delta);
                S[kk].y = fmaf(eg, S[kk].y, k4.y * delta);
                S[kk].z = fmaf(eg, S[kk].z, k4.z * delta);
                S[kk].w = fmaf(eg, S[kk].w, k4.w * delta);
                o0 = fmaf(q4.x, S[kk].x, o0);
                o1 = fmaf(q4.y, S[kk].y, o1);
                o2 = fmaf(q4.z, S[kk].z, o2);
                o3 = fmaf(q4.w, S[kk].w, o3);
            }
            o[(size_t)t * V_TOTAL + h * HEAD_DIM + vv] =
                scale * (o0 + o1 + o2 + o3);
        }
    }
}

// ---------------------------------------------------------------------------
// Gated RMSNorm: o = o * rsqrt(mean(o^2)+eps) * nw * silu(z), in-place.
// One wave per (t, v-head).
// ---------------------------------------------------------------------------
__global__ __launch_bounds__(64) void rmsnorm_gate_kernel(
    float* __restrict__ o, const float* __restrict__ z,
    const float* __restrict__ nw)
{
    const int row = blockIdx.x;       // t*32 + h
    float* p = o + (size_t)row * HEAD_DIM;
    const float* zp = z + (size_t)row * HEAD_DIM;
    const int lane = threadIdx.x;
    float2 v = *(float2*)(p + lane * 2);
    float s = v.x * v.x + v.y * v.y;
    for (int off = 32; off > 0; off >>= 1) s += __shfl_down(s, off);
    s = __shfl(s, 0);
    float inv = rsqrtf(s * (1.f / HEAD_DIM) + EPS_F);
    float2 zv = *(float2*)(zp + lane * 2);
    float2 wv = *(const float2*)(nw + lane * 2);
    v.x = v.x * inv * wv.x * (zv.x / (1.f + expf(-zv.x)));
    v.y = v.y * inv * wv.y * (zv.y / (1.f + expf(-zv.y)));
    *(float2*)(p + lane * 2) = v;
}

// ---------------------------------------------------------------------------
extern "C" void kernel_launch(void* const* d_in, const int* in_sizes, int n_in,
                              void* d_out, int out_size, void* d_ws,
                              size_t ws_size, hipStream_t stream)
{
    const float* hs    = (const float*)d_in[0];  // [2048,2048]
    const float* Wqkv  = (const float*)d_in[1];  // [8192,2048]
    const float* Wz    = (const float*)d_in[2];  // [4096,2048]
    const float* Wa    = (const float*)d_in[3];  // [32,2048]
    const float* Wb    = (const float*)d_in[4];  // [32,2048]
    const float* cw    = (const float*)d_in[5];  // [8192,4]
    const float* Wout  = (const float*)d_in[6];  // [2048,4096]
    const float* nw    = (const float*)d_in[7];  // [128]
    const float* A_log = (const float*)d_in[8];  // [32]
    const float* dtb   = (const float*)d_in[9];  // [32]
    float* out = (float*)d_out;

    float* ws    = (float*)d_ws;
    float* mixed = ws;                         // 2048*8192
    float* qkvb  = ws + (size_t)16777216;      // 2048*8192
    float* zb    = ws + (size_t)33554432;      // 2048*4096
    float* gb    = zb + (size_t)8388608;       // 2048*32
    float* bb    = gb + 65536;                 // 2048*32
    float* ob    = mixed;                      // reuse (mixed dead after conv)

    // 1. qkv projection: mixed = hs @ Wqkv^T   [2048, 8192]
    gemm_nt_64<<<dim3(QKV_TOTAL / 64, T_SEQ / 64), 256, 0, stream>>>(
        hs, Wqkv, mixed, T_SEQ, QKV_TOTAL, HIDDEN_D);
    // 2. z projection: z = hs @ Wz^T           [2048, 4096]
    gemm_nt_64<<<dim3(V_TOTAL / 64, T_SEQ / 64), 256, 0, stream>>>(
        hs, Wz, zb, T_SEQ, V_TOTAL, HIDDEN_D);
    // 3. a/b projections + gating -> g, beta   [2048, 32] each
    gating_kernel<<<T_SEQ, 64, 0, stream>>>(hs, Wa, Wb, A_log, dtb, gb, bb);
    // 4. causal conv + silu -> qkvb
    conv_silu_kernel<<<(T_SEQ * QKV_TOTAL) / 256, 256, 0, stream>>>(
        mixed, cw, qkvb);
    // 5. l2norm q,k in place
    l2norm_kernel<<<T_SEQ * 32, 64, 0, stream>>>(qkvb);
    // 6. gated delta-rule recurrence -> ob [2048, 4096]
    recurrence_kernel<<<64, 64, 0, stream>>>(qkvb, gb, bb, ob);
    // 7. gated rmsnorm in place on ob
    rmsnorm_gate_kernel<<<T_SEQ * NUM_VH, 64, 0, stream>>>(ob, zb, nw);
    // 8. out projection: out = ob @ Wout^T     [2048, 2048]
    gemm_nt_64<<<dim3(HIDDEN_D / 64, T_SEQ / 64), 256, 0, stream>>>(
        ob, Wout, out, T_SEQ, HIDDEN_D, V_TOTAL);
}

// Round 2
// 3667.412 us; speedup vs baseline: 2.2767x; 2.2767x over previous
//
#include <hip/hip_runtime.h>
#include <math.h>

#define T_SEQ     2048
#define HIDDEN_D  2048
#define NUM_KH    16
#define NUM_VH    32
#define HEAD_DIM  128
#define K_TOTAL   2048   // 16*128
#define V_TOTAL   4096   // 32*128
#define QKV_TOTAL 8192   // 2*K_TOTAL + V_TOTAL
#define EPS_F     1e-6f
#define CC        32     // chunk length
#define NV        32     // v-columns per block (Dv split 4 ways)

// ---------------------------------------------------------------------------
// Generic fp32 GEMM: C[M,N] = A[M,K] * B[N,K]^T   (both row-major, N-T form)
// ---------------------------------------------------------------------------
__global__ __launch_bounds__(256) void gemm_nt_64(
    const float* __restrict__ A, const float* __restrict__ B,
    float* __restrict__ C, int M, int N, int K)
{
    __shared__ float As[16][68];
    __shared__ float Bs[16][68];
    const int tid = threadIdx.x;
    const int m0 = blockIdx.y * 64;
    const int n0 = blockIdx.x * 64;
    const int tm = tid >> 4;
    const int tn = tid & 15;
    const int lr = tid >> 2;
    const int lc = (tid & 3) * 4;

    float acc[4][4];
#pragma unroll
    for (int i = 0; i < 4; ++i)
#pragma unroll
        for (int j = 0; j < 4; ++j) acc[i][j] = 0.f;

    for (int kt = 0; kt < K; kt += 16) {
        float4 av = *(const float4*)(A + (size_t)(m0 + lr) * K + kt + lc);
        float4 bv = *(const float4*)(B + (size_t)(n0 + lr) * K + kt + lc);
        As[lc + 0][lr] = av.x; As[lc + 1][lr] = av.y;
        As[lc + 2][lr] = av.z; As[lc + 3][lr] = av.w;
        Bs[lc + 0][lr] = bv.x; Bs[lc + 1][lr] = bv.y;
        Bs[lc + 2][lr] = bv.z; Bs[lc + 3][lr] = bv.w;
        __syncthreads();
#pragma unroll
        for (int kk = 0; kk < 16; ++kk) {
            float4 a4 = *(const float4*)&As[kk][tm * 4];
            float4 b4 = *(const float4*)&Bs[kk][tn * 4];
            float a[4] = {a4.x, a4.y, a4.z, a4.w};
            float b[4] = {b4.x, b4.y, b4.z, b4.w};
#pragma unroll
            for (int i = 0; i < 4; ++i)
#pragma unroll
                for (int j = 0; j < 4; ++j)
                    acc[i][j] = fmaf(a[i], b[j], acc[i][j]);
        }
        __syncthreads();
    }
#pragma unroll
    for (int i = 0; i < 4; ++i) {
        float4 o = make_float4(acc[i][0], acc[i][1], acc[i][2], acc[i][3]);
        *(float4*)(C + (size_t)(m0 + tm * 4 + i) * N + n0 + tn * 4) = o;
    }
}

// ---------------------------------------------------------------------------
// a/b projections fused with gating.
// ---------------------------------------------------------------------------
__global__ __launch_bounds__(64) void gating_kernel(
    const float* __restrict__ hs, const float* __restrict__ Wa,
    const float* __restrict__ Wb, const float* __restrict__ A_log,
    const float* __restrict__ dt_bias, float* __restrict__ g,
    float* __restrict__ beta)
{
    const int t = blockIdx.x;
    const int lane = threadIdx.x;
    const float* x = hs + (size_t)t * HIDDEN_D;
    for (int h = 0; h < NUM_VH; ++h) {
        const float* wa = Wa + (size_t)h * HIDDEN_D;
        const float* wb = Wb + (size_t)h * HIDDEN_D;
        float sa = 0.f, sb = 0.f;
        for (int i = lane; i < HIDDEN_D; i += 64) {
            float xv = x[i];
            sa = fmaf(xv, wa[i], sa);
            sb = fmaf(xv, wb[i], sb);
        }
        for (int off = 32; off > 0; off >>= 1) {
            sa += __shfl_down(sa, off);
            sb += __shfl_down(sb, off);
        }
        if (lane == 0) {
            float aa = sa + dt_bias[h];
            float sp = (aa > 20.f) ? aa : log1pf(expf(aa));
            g[t * NUM_VH + h] = -expf(A_log[h]) * sp;
            beta[t * NUM_VH + h] = 1.f / (1.f + expf(-sb));
        }
    }
}

// ---------------------------------------------------------------------------
// Depthwise causal conv1d (K=4) + SiLU.
// ---------------------------------------------------------------------------
__global__ __launch_bounds__(256) void conv_silu_kernel(
    const float* __restrict__ mixed, const float* __restrict__ cw,
    float* __restrict__ qkv)
{
    int idx = blockIdx.x * 256 + threadIdx.x;
    int c = idx & (QKV_TOTAL - 1);
    int t = idx >> 13;
    const float4 w = *(const float4*)(cw + (size_t)c * 4);
    float y = w.w * mixed[(size_t)t * QKV_TOTAL + c];
    if (t >= 1) y = fmaf(w.z, mixed[(size_t)(t - 1) * QKV_TOTAL + c], y);
    if (t >= 2) y = fmaf(w.y, mixed[(size_t)(t - 2) * QKV_TOTAL + c], y);
    if (t >= 3) y = fmaf(w.x, mixed[(size_t)(t - 3) * QKV_TOTAL + c], y);
    qkv[(size_t)t * QKV_TOTAL + c] = y / (1.f + expf(-y));
}

// ---------------------------------------------------------------------------
// L2-normalize q and k head rows in-place.
// ---------------------------------------------------------------------------
__global__ __launch_bounds__(64) void l2norm_kernel(float* __restrict__ qkv)
{
    const int row = blockIdx.x;
    const int t = row >> 5;
    const int r = row & 31;
    float* p = qkv + (size_t)t * QKV_TOTAL + r * HEAD_DIM;
    const int lane = threadIdx.x;
    float2 v = *(float2*)(p + lane * 2);
    float s = v.x * v.x + v.y * v.y;
    for (int off = 32; off > 0; off >>= 1) s += __shfl_down(s, off);
    s = __shfl(s, 0);
    float inv = rsqrtf(s + EPS_F);
    v.x *= inv; v.y *= inv;
    *(float2*)(p + lane * 2) = v;
}

// ---------------------------------------------------------------------------
// Chunk-parallel gated delta rule.  128 blocks = (head h, v-split of 32 cols),
// 256 threads.  Per chunk of CC=32 steps (all per-head, per-chunk):
//   cum_i = inclusive prefix of g;  r_ij = exp(cum_i - cum_j);  Lam_i = exp(cum_i)
//   W[i][j] = beta_i * r_ij * (k_i . k_j)      (j<i)
//   rhs_i   = beta_i * (v_i - Lam_i * (k_i . S0))
//   (I+W) Delta = rhs   (forward substitution)
//   O_i     = Lam_i * (q~_i . S0) + sum_{j<=i} r_ij (q~_i . k_j) Delta_j
//   S       = Lam_{C-1} * S0 + sum_j r_{C-1,j} k_j^T Delta_j
// All decay args are <=0 -> exp is safe; Lam underflow to 0 is exact decay.
// ---------------------------------------------------------------------------
__global__ __launch_bounds__(256) void chunk_recurrence(
    const float* __restrict__ qkv, const float* __restrict__ g,
    const float* __restrict__ beta, float* __restrict__ o)
{
    __shared__ float Kn[CC][132];     // k rows (b128-aligned rows)
    __shared__ float Qn[CC][132];     // scale*q rows
    __shared__ float Sm[HEAD_DIM][36];// state [kappa][nu]
    __shared__ float Wm[CC][CC];      // solve matrix
    __shared__ float Pt[CC][34];      // P transposed: Pt[j][i]
    __shared__ float Dl[CC][34];      // V -> rhs -> Delta
    __shared__ float cums[CC];
    __shared__ float betas[CC];
    __shared__ float rlast[CC];       // exp(cum_{C-1} - cum_j)

    const int tid = threadIdx.x;
    const int h   = blockIdx.x >> 2;
    const int V0  = (blockIdx.x & 3) * NV;
    const int kh  = h >> 1;                    // GQA: v-head h uses k-head h/2
    const float scale = 0.08838834764831845f;  // 128^-0.5

    // zero state
    {
        const int k0 = (tid >> 3) * 4, n0 = (tid & 7) * 4;
#pragma unroll
        for (int c = 0; c < 4; ++c)
#pragma unroll
            for (int d = 0; d < 4; ++d) Sm[k0 + c][n0 + d] = 0.f;
    }

    for (int cix = 0; cix < T_SEQ / CC; ++cix) {
        const int t0 = cix * CC;
        __syncthreads();   // protect Kn/Qn/Dl/Sm/cums from previous chunk's use

        // ---- A: stage chunk ----
        if (tid < CC) {
            float x = g[(size_t)(t0 + tid) * NUM_VH + h];
            float bv = beta[(size_t)(t0 + tid) * NUM_VH + h];
#pragma unroll
            for (int off = 1; off < 32; off <<= 1) {
                float n = __shfl_up(x, off);
                if (tid >= off) x += n;
            }
            cums[tid] = x;
            betas[tid] = bv;
            float c31 = __shfl(x, 31);
            rlast[tid] = expf(c31 - x);
        }
#pragma unroll
        for (int p = 0; p < 4; ++p) {
            int idx = p * 256 + tid;
            int i = idx >> 5, k4 = (idx & 31) * 4;
            const float* qr = qkv + (size_t)(t0 + i) * QKV_TOTAL + kh * HEAD_DIM + k4;
            float4 q4 = *(const float4*)qr;
            float4 k4v = *(const float4*)(qr + K_TOTAL);
            *(float4*)&Kn[i][k4] = k4v;
            q4.x *= scale; q4.y *= scale; q4.z *= scale; q4.w *= scale;
            *(float4*)&Qn[i][k4] = q4;
        }
        {
            int i = tid >> 3, n4 = (tid & 7) * 4;
            const float* vr = qkv + (size_t)(t0 + i) * QKV_TOTAL + 2 * K_TOTAL
                              + h * HEAD_DIM + V0 + n4;
            float4 v4 = *(const float4*)vr;
            Dl[i][n4] = v4.x; Dl[i][n4 + 1] = v4.y;
            Dl[i][n4 + 2] = v4.z; Dl[i][n4 + 3] = v4.w;
        }
        __syncthreads();

        // ---- B: W (decayed KK^T * beta) and Pt (decayed QK^T) ----
        {
            const int i0 = (tid >> 4) * 2, j0 = (tid & 15) * 2;
            float wa[2][2] = {{0.f, 0.f}, {0.f, 0.f}};
            float pa[2][2] = {{0.f, 0.f}, {0.f, 0.f}};
            for (int k = 0; k < HEAD_DIM; k += 4) {
                float4 a0 = *(const float4*)&Kn[i0][k];
                float4 a1 = *(const float4*)&Kn[i0 + 1][k];
                float4 b0 = *(const float4*)&Kn[j0][k];
                float4 b1 = *(const float4*)&Kn[j0 + 1][k];
                float4 c0 = *(const float4*)&Qn[i0][k];
                float4 c1 = *(const float4*)&Qn[i0 + 1][k];
                const float* ap0 = (const float*)&a0;
                const float* ap1 = (const float*)&a1;
                const float* bp0 = (const float*)&b0;
                const float* bp1 = (const float*)&b1;
                const float* cp0 = (const float*)&c0;
                const float* cp1 = (const float*)&c1;
#pragma unroll
                for (int cc = 0; cc < 4; ++cc) {
                    wa[0][0] = fmaf(ap0[cc], bp0[cc], wa[0][0]);
                    wa[0][1] = fmaf(ap0[cc], bp1[cc], wa[0][1]);
                    wa[1][0] = fmaf(ap1[cc], bp0[cc], wa[1][0]);
                    wa[1][1] = fmaf(ap1[cc], bp1[cc], wa[1][1]);
                    pa[0][0] = fmaf(cp0[cc], bp0[cc], pa[0][0]);
                    pa[0][1] = fmaf(cp0[cc], bp1[cc], pa[0][1]);
                    pa[1][0] = fmaf(cp1[cc], bp0[cc], pa[1][0]);
                    pa[1][1] = fmaf(cp1[cc], bp1[cc], pa[1][1]);
                }
            }
#pragma unroll
            for (int di = 0; di < 2; ++di)
#pragma unroll
                for (int dj = 0; dj < 2; ++dj) {
                    int i = i0 + di, j = j0 + dj;
                    float rr = expf(fminf(cums[i] - cums[j], 0.f));
                    Wm[i][j] = (j < i) ? betas[i] * rr * wa[di][dj] : 0.f;
                    Pt[j][i] = (j <= i) ? rr * pa[di][dj] : 0.f;
                }
        }

        // ---- C: rhs = beta(V - Lam K.S0), O1 = Lam Q.S0 (regs) ----
        const int ci0 = (tid >> 4) * 2, cn0 = (tid & 15) * 2;
        float o1[2][2] = {{0.f, 0.f}, {0.f, 0.f}};
        {
            float rs[2][2] = {{0.f, 0.f}, {0.f, 0.f}};
            for (int k = 0; k < HEAD_DIM; k += 4) {
                float4 a0 = *(const float4*)&Kn[ci0][k];
                float4 a1 = *(const float4*)&Kn[ci0 + 1][k];
                float4 q0 = *(const float4*)&Qn[ci0][k];
                float4 q1 = *(const float4*)&Qn[ci0 + 1][k];
                const float* ap0 = (const float*)&a0;
                const float* ap1 = (const float*)&a1;
                const float* qp0 = (const float*)&q0;
                const float* qp1 = (const float*)&q1;
#pragma unroll
                for (int cc = 0; cc < 4; ++cc) {
                    float2 s = *(const float2*)&Sm[k + cc][cn0];
                    rs[0][0] = fmaf(ap0[cc], s.x, rs[0][0]);
                    rs[0][1] = fmaf(ap0[cc], s.y, rs[0][1]);
                    rs[1][0] = fmaf(ap1[cc], s.x, rs[1][0]);
                    rs[1][1] = fmaf(ap1[cc], s.y, rs[1][1]);
                    o1[0][0] = fmaf(qp0[cc], s.x, o1[0][0]);
                    o1[0][1] = fmaf(qp0[cc], s.y, o1[0][1]);
                    o1[1][0] = fmaf(qp1[cc], s.x, o1[1][0]);
                    o1[1][1] = fmaf(qp1[cc], s.y, o1[1][1]);
                }
            }
#pragma unroll
            for (int di = 0; di < 2; ++di) {
                int i = ci0 + di;
                float lam = expf(cums[i]);
#pragma unroll
                for (int dn = 0; dn < 2; ++dn) {
                    int n = cn0 + dn;
                    Dl[i][n] = betas[i] * (Dl[i][n] - lam * rs[di][dn]);
                    o1[di][dn] *= lam;
                }
            }
        }
        __syncthreads();

        // ---- D: forward substitution (I+W) Delta = rhs, in place in Dl ----
        {
            const int col = tid >> 3, tk = tid & 7;
            for (int i = 1; i < CC; ++i) {
                float part = 0.f;
                for (int j = tk; j < i; j += 8)
                    part = fmaf(Wm[i][j], Dl[j][col], part);
                part += __shfl_xor(part, 4);
                part += __shfl_xor(part, 2);
                part += __shfl_xor(part, 1);
                if (tk == 0) Dl[i][col] -= part;
            }
        }
        __syncthreads();

        // ---- E1: O = O1 + P * Delta -> global ----
        {
            float oacc[2][2] = {{o1[0][0], o1[0][1]}, {o1[1][0], o1[1][1]}};
            for (int j = 0; j < CC; ++j) {
                float2 pv = *(const float2*)&Pt[j][ci0];
                float2 dv = *(const float2*)&Dl[j][cn0];
                oacc[0][0] = fmaf(pv.x, dv.x, oacc[0][0]);
                oacc[0][1] = fmaf(pv.x, dv.y, oacc[0][1]);
                oacc[1][0] = fmaf(pv.y, dv.x, oacc[1][0]);
                oacc[1][1] = fmaf(pv.y, dv.y, oacc[1][1]);
            }
#pragma unroll
            for (int di = 0; di < 2; ++di) {
                float2 ov = make_float2(oacc[di][0], oacc[di][1]);
                *(float2*)(o + (size_t)(t0 + ci0 + di) * V_TOTAL
                           + h * HEAD_DIM + V0 + cn0) = ov;
            }
        }

        // ---- E2: S = lamL*S + sum_j rlast_j k_j^T Delta_j ----
        {
            const int k0 = (tid >> 3) * 4, n0 = (tid & 7) * 4;
            const float lamL = expf(cums[CC - 1]);
            float acc[4][4];
#pragma unroll
            for (int c = 0; c < 4; ++c) {
                float4 s4 = *(const float4*)&Sm[k0 + c][n0];
                acc[c][0] = lamL * s4.x; acc[c][1] = lamL * s4.y;
                acc[c][2] = lamL * s4.z; acc[c][3] = lamL * s4.w;
            }
            for (int j = 0; j < CC; ++j) {
                float coef = rlast[j];
                float4 kv = *(const float4*)&Kn[j][k0];
                float2 d0 = *(const float2*)&Dl[j][n0];
                float2 d1 = *(const float2*)&Dl[j][n0 + 2];
                float cd[4] = {coef * d0.x, coef * d0.y, coef * d1.x, coef * d1.y};
                const float* kp = (const float*)&kv;
#pragma unroll
                for (int c = 0; c < 4; ++c)
#pragma unroll
                    for (int d = 0; d < 4; ++d)
                        acc[c][d] = fmaf(kp[c], cd[d], acc[c][d]);
            }
#pragma unroll
            for (int c = 0; c < 4; ++c) {
                float4 s4 = make_float4(acc[c][0], acc[c][1], acc[c][2], acc[c][3]);
                *(float4*)&Sm[k0 + c][n0] = s4;
            }
        }
    }
}

// ---------------------------------------------------------------------------
// Gated RMSNorm.
// ---------------------------------------------------------------------------
__global__ __launch_bounds__(64) void rmsnorm_gate_kernel(
    float* __restrict__ o, const float* __restrict__ z,
    const float* __restrict__ nw)
{
    const int row = blockIdx.x;
    float* p = o + (size_t)row * HEAD_DIM;
    const float* zp = z + (size_t)row * HEAD_DIM;
    const int lane = threadIdx.x;
    float2 v = *(float2*)(p + lane * 2);
    float s = v.x * v.x + v.y * v.y;
    for (int off = 32; off > 0; off >>= 1) s += __shfl_down(s, off);
    s = __shfl(s, 0);
    float inv = rsqrtf(s * (1.f / HEAD_DIM) + EPS_F);
    float2 zv = *(float2*)(zp + lane * 2);
    float2 wv = *(const float2*)(nw + lane * 2);
    v.x = v.x * inv * wv.x * (zv.x / (1.f + expf(-zv.x)));
    v.y = v.y * inv * wv.y * (zv.y / (1.f + expf(-zv.y)));
    *(float2*)(p + lane * 2) = v;
}

// ---------------------------------------------------------------------------
extern "C" void kernel_launch(void* const* d_in, const int* in_sizes, int n_in,
                              void* d_out, int out_size, void* d_ws,
                              size_t ws_size, hipStream_t stream)
{
    const float* hs    = (const float*)d_in[0];
    const float* Wqkv  = (const float*)d_in[1];
    const float* Wz    = (const float*)d_in[2];
    const float* Wa    = (const float*)d_in[3];
    const float* Wb    = (const float*)d_in[4];
    const float* cw    = (const float*)d_in[5];
    const float* Wout  = (const float*)d_in[6];
    const float* nw    = (const float*)d_in[7];
    const float* A_log = (const float*)d_in[8];
    const float* dtb   = (const float*)d_in[9];
    float* out = (float*)d_out;

    float* ws    = (float*)d_ws;
    float* mixed = ws;                         // 2048*8192
    float* qkvb  = ws + (size_t)16777216;      // 2048*8192
    float* zb    = ws + (size_t)33554432;      // 2048*4096
    float* gb    = zb + (size_t)8388608;       // 2048*32
    float* bb    = gb + 65536;                 // 2048*32
    float* ob    = mixed;                      // reuse (mixed dead after conv)

    gemm_nt_64<<<dim3(QKV_TOTAL / 64, T_SEQ / 64), 256, 0, stream>>>(
        hs, Wqkv, mixed, T_SEQ, QKV_TOTAL, HIDDEN_D);
    gemm_nt_64<<<dim3(V_TOTAL / 64, T_SEQ / 64), 256, 0, stream>>>(
        hs, Wz, zb, T_SEQ, V_TOTAL, HIDDEN_D);
    gating_kernel<<<T_SEQ, 64, 0, stream>>>(hs, Wa, Wb, A_log, dtb, gb, bb);
    conv_silu_kernel<<<(T_SEQ * QKV_TOTAL) / 256, 256, 0, stream>>>(
        mixed, cw, qkvb);
    l2norm_kernel<<<T_SEQ * 32, 64, 0, stream>>>(qkvb);
    chunk_recurrence<<<NUM_VH * 4, 256, 0, stream>>>(qkvb, gb, bb, ob);
    rmsnorm_gate_kernel<<<T_SEQ * NUM_VH, 64, 0, stream>>>(ob, zb, nw);
    gemm_nt_64<<<dim3(HIDDEN_D / 64, T_SEQ / 64), 256, 0, stream>>>(
        ob, Wout, out, T_SEQ, HIDDEN_D, V_TOTAL);
}

// Round 3
// 1965.749 us; speedup vs baseline: 4.2475x; 1.8657x over previous
//
#include <hip/hip_runtime.h>
#include <math.h>

#define T_SEQ     2048
#define HIDDEN_D  2048
#define NUM_KH    16
#define NUM_VH    32
#define HEAD_DIM  128
#define K_TOTAL   2048   // 16*128
#define V_TOTAL   4096   // 32*128
#define QKV_TOTAL 8192   // 2*K_TOTAL + V_TOTAL
#define EPS_F     1e-6f
#define CC        32     // chunk length
#define NV        32     // v-columns per block (Dv split 4 ways)

typedef __attribute__((ext_vector_type(4))) float f32x4;
typedef __attribute__((ext_vector_type(8))) short s16x8;

__device__ __forceinline__ unsigned short f2bf(float f) {
    unsigned int u = __float_as_uint(f);
    u += 0x7FFFu + ((u >> 16) & 1u);   // RNE (inputs are finite/well-behaved)
    return (unsigned short)(u >> 16);
}

// ---------------------------------------------------------------------------
// fp32 -> bf16 cast, float4/ushort4 vectorized.  n4 = count in float4 units.
// ---------------------------------------------------------------------------
__global__ __launch_bounds__(256) void cast_bf16_kernel(
    const float* __restrict__ src, unsigned short* __restrict__ dst, int n4)
{
    int idx = blockIdx.x * 256 + threadIdx.x;
    if (idx >= n4) return;
    float4 v = ((const float4*)src)[idx];
    ushort4 o;
    o.x = f2bf(v.x); o.y = f2bf(v.y); o.z = f2bf(v.z); o.w = f2bf(v.w);
    ((ushort4*)dst)[idx] = o;
}

// ---------------------------------------------------------------------------
// bf16 MFMA GEMM (NT): C[M,N] fp32 = A[M,K]bf16 * B[N,K]bf16^T.
// 128x128 tile, BK=64, 256 threads = 4 waves (2x2 of 64x64), m97 structure:
// global_load_lds width-16 staging, 16x16x32 bf16 MFMA, 4x4 tiles/wave.
// M,N % 128 == 0, K % 64 == 0 (true for all three projections).
// ---------------------------------------------------------------------------
__global__ __launch_bounds__(256) void gemm_bt_bf16(
    const unsigned short* __restrict__ A, const unsigned short* __restrict__ B,
    float* __restrict__ C, int M, int N, int K)
{
    __shared__ unsigned short As[128 * 64];
    __shared__ unsigned short Bs[128 * 64];
    const int tid  = threadIdx.x;
    const int wave = tid >> 6;
    const int lane = tid & 63;
    const int m0 = blockIdx.y * 128;
    const int n0 = blockIdx.x * 128;
    const int wm = (wave >> 1) * 64;
    const int wn = (wave & 1) * 64;

    f32x4 acc[4][4];
    f32x4 zero = {0.f, 0.f, 0.f, 0.f};
#pragma unroll
    for (int i = 0; i < 4; ++i)
#pragma unroll
        for (int j = 0; j < 4; ++j) acc[i][j] = zero;

    // staging geometry: each wave stages 32 rows of A and 32 of B as 4 loads
    // of 1KB (8 rows x 128B); lane i -> row r0 + (i>>3), col (i&7)*8 bf16,
    // which is exactly LDS base + i*16 bytes (global_load_lds requirement).
    const int srow = lane >> 3;
    const int scol = (lane & 7) * 8;
    const int rm = lane & 15;
    const int koq = (lane >> 4) * 8;

    for (int kt = 0; kt < K; kt += 64) {
#pragma unroll
        for (int l = 0; l < 4; ++l) {
            const int r0 = wave * 32 + l * 8;
            const unsigned short* ga =
                A + (size_t)(m0 + r0 + srow) * K + kt + scol;
            const unsigned short* gb =
                B + (size_t)(n0 + r0 + srow) * K + kt + scol;
            __builtin_amdgcn_global_load_lds(
                (const __attribute__((address_space(1))) void*)ga,
                (__attribute__((address_space(3))) void*)&As[r0 * 64], 16, 0, 0);
            __builtin_amdgcn_global_load_lds(
                (const __attribute__((address_space(1))) void*)gb,
                (__attribute__((address_space(3))) void*)&Bs[r0 * 64], 16, 0, 0);
        }
        __syncthreads();   // compiler emits vmcnt(0) drain before barrier

#pragma unroll
        for (int ks = 0; ks < 2; ++ks) {
            const int ko = ks * 32 + koq;
            s16x8 af[4], bfr[4];
#pragma unroll
            for (int i = 0; i < 4; ++i) {
                af[i]  = *(const s16x8*)&As[(wm + i * 16 + rm) * 64 + ko];
                bfr[i] = *(const s16x8*)&Bs[(wn + i * 16 + rm) * 64 + ko];
            }
#pragma unroll
            for (int i = 0; i < 4; ++i)
#pragma unroll
                for (int j = 0; j < 4; ++j)
                    acc[i][j] = __builtin_amdgcn_mfma_f32_16x16x32_bf16(
                        af[i], bfr[j], acc[i][j], 0, 0, 0);
        }
        __syncthreads();   // all reads done before next stage overwrites
    }

    // epilogue: C/D layout col=lane&15, row=(lane>>4)*4+reg
    const int cr = (lane >> 4) * 4;
    const int ccol = lane & 15;
#pragma unroll
    for (int i = 0; i < 4; ++i)
#pragma unroll
        for (int j = 0; j < 4; ++j) {
#pragma unroll
            for (int r = 0; r < 4; ++r)
                C[(size_t)(m0 + wm + i * 16 + cr + r) * N
                  + n0 + wn + j * 16 + ccol] = acc[i][j][r];
        }
}

// ---------------------------------------------------------------------------
// a/b projections fused with gating.
// ---------------------------------------------------------------------------
__global__ __launch_bounds__(64) void gating_kernel(
    const float* __restrict__ hs, const float* __restrict__ Wa,
    const float* __restrict__ Wb, const float* __restrict__ A_log,
    const float* __restrict__ dt_bias, float* __restrict__ g,
    float* __restrict__ beta)
{
    const int t = blockIdx.x;
    const int lane = threadIdx.x;
    const float* x = hs + (size_t)t * HIDDEN_D;
    for (int h = 0; h < NUM_VH; ++h) {
        const float* wa = Wa + (size_t)h * HIDDEN_D;
        const float* wb = Wb + (size_t)h * HIDDEN_D;
        float sa = 0.f, sb = 0.f;
        for (int i = lane; i < HIDDEN_D; i += 64) {
            float xv = x[i];
            sa = fmaf(xv, wa[i], sa);
            sb = fmaf(xv, wb[i], sb);
        }
        for (int off = 32; off > 0; off >>= 1) {
            sa += __shfl_down(sa, off);
            sb += __shfl_down(sb, off);
        }
        if (lane == 0) {
            float aa = sa + dt_bias[h];
            float sp = (aa > 20.f) ? aa : log1pf(expf(aa));
            g[t * NUM_VH + h] = -expf(A_log[h]) * sp;
            beta[t * NUM_VH + h] = 1.f / (1.f + expf(-sb));
        }
    }
}

// ---------------------------------------------------------------------------
// Depthwise causal conv1d (K=4) + SiLU.
// ---------------------------------------------------------------------------
__global__ __launch_bounds__(256) void conv_silu_kernel(
    const float* __restrict__ mixed, const float* __restrict__ cw,
    float* __restrict__ qkv)
{
    int idx = blockIdx.x * 256 + threadIdx.x;
    int c = idx & (QKV_TOTAL - 1);
    int t = idx >> 13;
    const float4 w = *(const float4*)(cw + (size_t)c * 4);
    float y = w.w * mixed[(size_t)t * QKV_TOTAL + c];
    if (t >= 1) y = fmaf(w.z, mixed[(size_t)(t - 1) * QKV_TOTAL + c], y);
    if (t >= 2) y = fmaf(w.y, mixed[(size_t)(t - 2) * QKV_TOTAL + c], y);
    if (t >= 3) y = fmaf(w.x, mixed[(size_t)(t - 3) * QKV_TOTAL + c], y);
    qkv[(size_t)t * QKV_TOTAL + c] = y / (1.f + expf(-y));
}

// ---------------------------------------------------------------------------
// L2-normalize q and k head rows in-place.
// ---------------------------------------------------------------------------
__global__ __launch_bounds__(64) void l2norm_kernel(float* __restrict__ qkv)
{
    const int row = blockIdx.x;
    const int t = row >> 5;
    const int r = row & 31;
    float* p = qkv + (size_t)t * QKV_TOTAL + r * HEAD_DIM;
    const int lane = threadIdx.x;
    float2 v = *(float2*)(p + lane * 2);
    float s = v.x * v.x + v.y * v.y;
    for (int off = 32; off > 0; off >>= 1) s += __shfl_down(s, off);
    s = __shfl(s, 0);
    float inv = rsqrtf(s + EPS_F);
    v.x *= inv; v.y *= inv;
    *(float2*)(p + lane * 2) = v;
}

// ---------------------------------------------------------------------------
// Chunk-parallel gated delta rule (unchanged from Round 2; see derivation).
// ---------------------------------------------------------------------------
__global__ __launch_bounds__(256) void chunk_recurrence(
    const float* __restrict__ qkv, const float* __restrict__ g,
    const float* __restrict__ beta, float* __restrict__ o)
{
    __shared__ float Kn[CC][132];
    __shared__ float Qn[CC][132];
    __shared__ float Sm[HEAD_DIM][36];
    __shared__ float Wm[CC][CC];
    __shared__ float Pt[CC][34];
    __shared__ float Dl[CC][34];
    __shared__ float cums[CC];
    __shared__ float betas[CC];
    __shared__ float rlast[CC];

    const int tid = threadIdx.x;
    const int h   = blockIdx.x >> 2;
    const int V0  = (blockIdx.x & 3) * NV;
    const int kh  = h >> 1;
    const float scale = 0.08838834764831845f;

    {
        const int k0 = (tid >> 3) * 4, n0 = (tid & 7) * 4;
#pragma unroll
        for (int c = 0; c < 4; ++c)
#pragma unroll
            for (int d = 0; d < 4; ++d) Sm[k0 + c][n0 + d] = 0.f;
    }

    for (int cix = 0; cix < T_SEQ / CC; ++cix) {
        const int t0 = cix * CC;
        __syncthreads();

        if (tid < CC) {
            float x = g[(size_t)(t0 + tid) * NUM_VH + h];
            float bv = beta[(size_t)(t0 + tid) * NUM_VH + h];
#pragma unroll
            for (int off = 1; off < 32; off <<= 1) {
                float n = __shfl_up(x, off);
                if (tid >= off) x += n;
            }
            cums[tid] = x;
            betas[tid] = bv;
            float c31 = __shfl(x, 31);
            rlast[tid] = expf(c31 - x);
        }
#pragma unroll
        for (int p = 0; p < 4; ++p) {
            int idx = p * 256 + tid;
            int i = idx >> 5, k4 = (idx & 31) * 4;
            const float* qr = qkv + (size_t)(t0 + i) * QKV_TOTAL + kh * HEAD_DIM + k4;
            float4 q4 = *(const float4*)qr;
            float4 k4v = *(const float4*)(qr + K_TOTAL);
            *(float4*)&Kn[i][k4] = k4v;
            q4.x *= scale; q4.y *= scale; q4.z *= scale; q4.w *= scale;
            *(float4*)&Qn[i][k4] = q4;
        }
        {
            int i = tid >> 3, n4 = (tid & 7) * 4;
            const float* vr = qkv + (size_t)(t0 + i) * QKV_TOTAL + 2 * K_TOTAL
                              + h * HEAD_DIM + V0 + n4;
            float4 v4 = *(const float4*)vr;
            Dl[i][n4] = v4.x; Dl[i][n4 + 1] = v4.y;
            Dl[i][n4 + 2] = v4.z; Dl[i][n4 + 3] = v4.w;
        }
        __syncthreads();

        {
            const int i0 = (tid >> 4) * 2, j0 = (tid & 15) * 2;
            float wa[2][2] = {{0.f, 0.f}, {0.f, 0.f}};
            float pa[2][2] = {{0.f, 0.f}, {0.f, 0.f}};
            for (int k = 0; k < HEAD_DIM; k += 4) {
                float4 a0 = *(const float4*)&Kn[i0][k];
                float4 a1 = *(const float4*)&Kn[i0 + 1][k];
                float4 b0 = *(const float4*)&Kn[j0][k];
                float4 b1 = *(const float4*)&Kn[j0 + 1][k];
                float4 c0 = *(const float4*)&Qn[i0][k];
                float4 c1 = *(const float4*)&Qn[i0 + 1][k];
                const float* ap0 = (const float*)&a0;
                const float* ap1 = (const float*)&a1;
                const float* bp0 = (const float*)&b0;
                const float* bp1 = (const float*)&b1;
                const float* cp0 = (const float*)&c0;
                const float* cp1 = (const float*)&c1;
#pragma unroll
                for (int cc = 0; cc < 4; ++cc) {
                    wa[0][0] = fmaf(ap0[cc], bp0[cc], wa[0][0]);
                    wa[0][1] = fmaf(ap0[cc], bp1[cc], wa[0][1]);
                    wa[1][0] = fmaf(ap1[cc], bp0[cc], wa[1][0]);
                    wa[1][1] = fmaf(ap1[cc], bp1[cc], wa[1][1]);
                    pa[0][0] = fmaf(cp0[cc], bp0[cc], pa[0][0]);
                    pa[0][1] = fmaf(cp0[cc], bp1[cc], pa[0][1]);
                    pa[1][0] = fmaf(cp1[cc], bp0[cc], pa[1][0]);
                    pa[1][1] = fmaf(cp1[cc], bp1[cc], pa[1][1]);
                }
            }
#pragma unroll
            for (int di = 0; di < 2; ++di)
#pragma unroll
                for (int dj = 0; dj < 2; ++dj) {
                    int i = i0 + di, j = j0 + dj;
                    float rr = expf(fminf(cums[i] - cums[j], 0.f));
                    Wm[i][j] = (j < i) ? betas[i] * rr * wa[di][dj] : 0.f;
                    Pt[j][i] = (j <= i) ? rr * pa[di][dj] : 0.f;
                }
        }

        const int ci0 = (tid >> 4) * 2, cn0 = (tid & 15) * 2;
        float o1[2][2] = {{0.f, 0.f}, {0.f, 0.f}};
        {
            float rs[2][2] = {{0.f, 0.f}, {0.f, 0.f}};
            for (int k = 0; k < HEAD_DIM; k += 4) {
                float4 a0 = *(const float4*)&Kn[ci0][k];
                float4 a1 = *(const float4*)&Kn[ci0 + 1][k];
                float4 q0 = *(const float4*)&Qn[ci0][k];
                float4 q1 = *(const float4*)&Qn[ci0 + 1][k];
                const float* ap0 = (const float*)&a0;
                const float* ap1 = (const float*)&a1;
                const float* qp0 = (const float*)&q0;
                const float* qp1 = (const float*)&q1;
#pragma unroll
                for (int cc = 0; cc < 4; ++cc) {
                    float2 s = *(const float2*)&Sm[k + cc][cn0];
                    rs[0][0] = fmaf(ap0[cc], s.x, rs[0][0]);
                    rs[0][1] = fmaf(ap0[cc], s.y, rs[0][1]);
                    rs[1][0] = fmaf(ap1[cc], s.x, rs[1][0]);
                    rs[1][1] = fmaf(ap1[cc], s.y, rs[1][1]);
                    o1[0][0] = fmaf(qp0[cc], s.x, o1[0][0]);
                    o1[0][1] = fmaf(qp0[cc], s.y, o1[0][1]);
                    o1[1][0] = fmaf(qp1[cc], s.x, o1[1][0]);
                    o1[1][1] = fmaf(qp1[cc], s.y, o1[1][1]);
                }
            }
#pragma unroll
            for (int di = 0; di < 2; ++di) {
                int i = ci0 + di;
                float lam = expf(cums[i]);
#pragma unroll
                for (int dn = 0; dn < 2; ++dn) {
                    int n = cn0 + dn;
                    Dl[i][n] = betas[i] * (Dl[i][n] - lam * rs[di][dn]);
                    o1[di][dn] *= lam;
                }
            }
        }
        __syncthreads();

        {
            const int col = tid >> 3, tk = tid & 7;
            for (int i = 1; i < CC; ++i) {
                float part = 0.f;
                for (int j = tk; j < i; j += 8)
                    part = fmaf(Wm[i][j], Dl[j][col], part);
                part += __shfl_xor(part, 4);
                part += __shfl_xor(part, 2);
                part += __shfl_xor(part, 1);
                if (tk == 0) Dl[i][col] -= part;
            }
        }
        __syncthreads();

        {
            float oacc[2][2] = {{o1[0][0], o1[0][1]}, {o1[1][0], o1[1][1]}};
            for (int j = 0; j < CC; ++j) {
                float2 pv = *(const float2*)&Pt[j][ci0];
                float2 dv = *(const float2*)&Dl[j][cn0];
                oacc[0][0] = fmaf(pv.x, dv.x, oacc[0][0]);
                oacc[0][1] = fmaf(pv.x, dv.y, oacc[0][1]);
                oacc[1][0] = fmaf(pv.y, dv.x, oacc[1][0]);
                oacc[1][1] = fmaf(pv.y, dv.y, oacc[1][1]);
            }
#pragma unroll
            for (int di = 0; di < 2; ++di) {
                float2 ov = make_float2(oacc[di][0], oacc[di][1]);
                *(float2*)(o + (size_t)(t0 + ci0 + di) * V_TOTAL
                           + h * HEAD_DIM + V0 + cn0) = ov;
            }
        }

        {
            const int k0 = (tid >> 3) * 4, n0 = (tid & 7) * 4;
            const float lamL = expf(cums[CC - 1]);
            float acc[4][4];
#pragma unroll
            for (int c = 0; c < 4; ++c) {
                float4 s4 = *(const float4*)&Sm[k0 + c][n0];
                acc[c][0] = lamL * s4.x; acc[c][1] = lamL * s4.y;
                acc[c][2] = lamL * s4.z; acc[c][3] = lamL * s4.w;
            }
            for (int j = 0; j < CC; ++j) {
                float coef = rlast[j];
                float4 kv = *(const float4*)&Kn[j][k0];
                float2 d0 = *(const float2*)&Dl[j][n0];
                float2 d1 = *(const float2*)&Dl[j][n0 + 2];
                float cd[4] = {coef * d0.x, coef * d0.y, coef * d1.x, coef * d1.y};
                const float* kp = (const float*)&kv;
#pragma unroll
                for (int c = 0; c < 4; ++c)
#pragma unroll
                    for (int d = 0; d < 4; ++d)
                        acc[c][d] = fmaf(kp[c], cd[d], acc[c][d]);
            }
#pragma unroll
            for (int c = 0; c < 4; ++c) {
                float4 s4 = make_float4(acc[c][0], acc[c][1], acc[c][2], acc[c][3]);
                *(float4*)&Sm[k0 + c][n0] = s4;
            }
        }
    }
}

// ---------------------------------------------------------------------------
// Gated RMSNorm.
// ---------------------------------------------------------------------------
__global__ __launch_bounds__(64) void rmsnorm_gate_kernel(
    float* __restrict__ o, const float* __restrict__ z,
    const float* __restrict__ nw)
{
    const int row = blockIdx.x;
    float* p = o + (size_t)row * HEAD_DIM;
    const float* zp = z + (size_t)row * HEAD_DIM;
    const int lane = threadIdx.x;
    float2 v = *(float2*)(p + lane * 2);
    float s = v.x * v.x + v.y * v.y;
    for (int off = 32; off > 0; off >>= 1) s += __shfl_down(s, off);
    s = __shfl(s, 0);
    float inv = rsqrtf(s * (1.f / HEAD_DIM) + EPS_F);
    float2 zv = *(float2*)(zp + lane * 2);
    float2 wv = *(const float2*)(nw + lane * 2);
    v.x = v.x * inv * wv.x * (zv.x / (1.f + expf(-zv.x)));
    v.y = v.y * inv * wv.y * (zv.y / (1.f + expf(-zv.y)));
    *(float2*)(p + lane * 2) = v;
}

// ---------------------------------------------------------------------------
extern "C" void kernel_launch(void* const* d_in, const int* in_sizes, int n_in,
                              void* d_out, int out_size, void* d_ws,
                              size_t ws_size, hipStream_t stream)
{
    const float* hs    = (const float*)d_in[0];
    const float* Wqkv  = (const float*)d_in[1];
    const float* Wz    = (const float*)d_in[2];
    const float* Wa    = (const float*)d_in[3];
    const float* Wb    = (const float*)d_in[4];
    const float* cw    = (const float*)d_in[5];
    const float* Wout  = (const float*)d_in[6];
    const float* nw    = (const float*)d_in[7];
    const float* A_log = (const float*)d_in[8];
    const float* dtb   = (const float*)d_in[9];
    float* out = (float*)d_out;

    float* F     = (float*)d_ws;
    float* mixed = F;                          // [0, 16777216) fp32
    float* qkvb  = F + (size_t)16777216;       // [16777216, 33554432)
    float* zb    = F + (size_t)33554432;       // [33554432, 41943040)
    float* gb    = F + (size_t)41943040;       // [.., +65536)
    float* bb    = F + (size_t)42008576;       // [.., +65536)
    float* ob    = mixed;                      // reuse (mixed dead after conv)

    // bf16 buffers live in temporally-dead fp32 regions (footprint unchanged):
    // hs_bf/Wqkv_bf/Wz_bf inside qkvb (qkvb first written by conv, after the
    // two bf16 GEMMs consumed them); ob_bf/Wout_bf inside zb (zb dead after
    // rmsnorm, casts run after it).
    unsigned short* hs_bf   = (unsigned short*)(F + (size_t)16777216); //  4,194,304 elems
    unsigned short* Wqkv_bf = (unsigned short*)(F + (size_t)18874368); // 16,777,216
    unsigned short* Wz_bf   = (unsigned short*)(F + (size_t)27262976); //  8,388,608
    unsigned short* ob_bf   = (unsigned short*)(F + (size_t)33554432); //  8,388,608
    unsigned short* Wout_bf = (unsigned short*)(F + (size_t)37748736); //  8,388,608

    // 1. casts for the two input-side GEMMs
    cast_bf16_kernel<<<1048576 / 256, 256, 0, stream>>>(hs, hs_bf, 1048576);
    cast_bf16_kernel<<<4194304 / 256, 256, 0, stream>>>(Wqkv, Wqkv_bf, 4194304);
    cast_bf16_kernel<<<2097152 / 256, 256, 0, stream>>>(Wz, Wz_bf, 2097152);
    // 2. qkv projection (bf16 MFMA): mixed = hs @ Wqkv^T
    gemm_bt_bf16<<<dim3(QKV_TOTAL / 128, T_SEQ / 128), 256, 0, stream>>>(
        hs_bf, Wqkv_bf, mixed, T_SEQ, QKV_TOTAL, HIDDEN_D);
    // 3. z projection (bf16 MFMA)
    gemm_bt_bf16<<<dim3(V_TOTAL / 128, T_SEQ / 128), 256, 0, stream>>>(
        hs_bf, Wz_bf, zb, T_SEQ, V_TOTAL, HIDDEN_D);
    // 4. gating (fp32)
    gating_kernel<<<T_SEQ, 64, 0, stream>>>(hs, Wa, Wb, A_log, dtb, gb, bb);
    // 5. conv + silu
    conv_silu_kernel<<<(T_SEQ * QKV_TOTAL) / 256, 256, 0, stream>>>(
        mixed, cw, qkvb);
    // 6. l2norm q,k
    l2norm_kernel<<<T_SEQ * 32, 64, 0, stream>>>(qkvb);
    // 7. chunked gated delta rule
    chunk_recurrence<<<NUM_VH * 4, 256, 0, stream>>>(qkvb, gb, bb, ob);
    // 8. gated rmsnorm (consumes zb)
    rmsnorm_gate_kernel<<<T_SEQ * NUM_VH, 64, 0, stream>>>(ob, zb, nw);
    // 9. casts for the output GEMM (zb region now dead)
    cast_bf16_kernel<<<2097152 / 256, 256, 0, stream>>>(ob, ob_bf, 2097152);
    cast_bf16_kernel<<<2097152 / 256, 256, 0, stream>>>(Wout, Wout_bf, 2097152);
    // 10. out projection (bf16 MFMA): out = ob @ Wout^T
    gemm_bt_bf16<<<dim3(HIDDEN_D / 128, T_SEQ / 128), 256, 0, stream>>>(
        ob_bf, Wout_bf, out, T_SEQ, HIDDEN_D, V_TOTAL);
}

// Round 4
// 1243.043 us; speedup vs baseline: 6.7169x; 1.5814x over previous
//
#include <hip/hip_runtime.h>
#include <math.h>

#define T_SEQ     2048
#define HIDDEN_D  2048
#define NUM_KH    16
#define NUM_VH    32
#define HEAD_DIM  128
#define K_TOTAL   2048   // 16*128
#define V_TOTAL   4096   // 32*128
#define QKV_TOTAL 8192   // 2*K_TOTAL + V_TOTAL
#define EPS_F     1e-6f
#define CC        32     // chunk length
#define NCHUNK    (T_SEQ / CC)
#define NV        16     // v-columns per p2 block (Dv split 8 ways)

typedef __attribute__((ext_vector_type(4))) float f32x4;
typedef __attribute__((ext_vector_type(8))) short s16x8;

__device__ __forceinline__ unsigned short f2bf(float f) {
    unsigned int u = __float_as_uint(f);
    u += 0x7FFFu + ((u >> 16) & 1u);   // RNE
    return (unsigned short)(u >> 16);
}

// ---------------------------------------------------------------------------
// fp32 -> bf16 cast.
// ---------------------------------------------------------------------------
__global__ __launch_bounds__(256) void cast_bf16_kernel(
    const float* __restrict__ src, unsigned short* __restrict__ dst, int n4)
{
    int idx = blockIdx.x * 256 + threadIdx.x;
    if (idx >= n4) return;
    float4 v = ((const float4*)src)[idx];
    ushort4 o;
    o.x = f2bf(v.x); o.y = f2bf(v.y); o.z = f2bf(v.z); o.w = f2bf(v.w);
    ((ushort4*)dst)[idx] = o;
}

// ---------------------------------------------------------------------------
// bf16 MFMA GEMM (NT): C[M,N] fp32 = A[M,K]bf16 * B[N,K]bf16^T. (unchanged)
// ---------------------------------------------------------------------------
__global__ __launch_bounds__(256) void gemm_bt_bf16(
    const unsigned short* __restrict__ A, const unsigned short* __restrict__ B,
    float* __restrict__ C, int M, int N, int K)
{
    __shared__ unsigned short As[128 * 64];
    __shared__ unsigned short Bs[128 * 64];
    const int tid  = threadIdx.x;
    const int wave = tid >> 6;
    const int lane = tid & 63;
    const int m0 = blockIdx.y * 128;
    const int n0 = blockIdx.x * 128;
    const int wm = (wave >> 1) * 64;
    const int wn = (wave & 1) * 64;

    f32x4 acc[4][4];
    f32x4 zero = {0.f, 0.f, 0.f, 0.f};
#pragma unroll
    for (int i = 0; i < 4; ++i)
#pragma unroll
        for (int j = 0; j < 4; ++j) acc[i][j] = zero;

    const int srow = lane >> 3;
    const int scol = (lane & 7) * 8;
    const int rm = lane & 15;
    const int koq = (lane >> 4) * 8;

    for (int kt = 0; kt < K; kt += 64) {
#pragma unroll
        for (int l = 0; l < 4; ++l) {
            const int r0 = wave * 32 + l * 8;
            const unsigned short* ga =
                A + (size_t)(m0 + r0 + srow) * K + kt + scol;
            const unsigned short* gb =
                B + (size_t)(n0 + r0 + srow) * K + kt + scol;
            __builtin_amdgcn_global_load_lds(
                (const __attribute__((address_space(1))) void*)ga,
                (__attribute__((address_space(3))) void*)&As[r0 * 64], 16, 0, 0);
            __builtin_amdgcn_global_load_lds(
                (const __attribute__((address_space(1))) void*)gb,
                (__attribute__((address_space(3))) void*)&Bs[r0 * 64], 16, 0, 0);
        }
        __syncthreads();

#pragma unroll
        for (int ks = 0; ks < 2; ++ks) {
            const int ko = ks * 32 + koq;
            s16x8 af[4], bfr[4];
#pragma unroll
            for (int i = 0; i < 4; ++i) {
                af[i]  = *(const s16x8*)&As[(wm + i * 16 + rm) * 64 + ko];
                bfr[i] = *(const s16x8*)&Bs[(wn + i * 16 + rm) * 64 + ko];
            }
#pragma unroll
            for (int i = 0; i < 4; ++i)
#pragma unroll
                for (int j = 0; j < 4; ++j)
                    acc[i][j] = __builtin_amdgcn_mfma_f32_16x16x32_bf16(
                        af[i], bfr[j], acc[i][j], 0, 0, 0);
        }
        __syncthreads();
    }

    const int cr = (lane >> 4) * 4;
    const int ccol = lane & 15;
#pragma unroll
    for (int i = 0; i < 4; ++i)
#pragma unroll
        for (int j = 0; j < 4; ++j) {
#pragma unroll
            for (int r = 0; r < 4; ++r)
                C[(size_t)(m0 + wm + i * 16 + cr + r) * N
                  + n0 + wn + j * 16 + ccol] = acc[i][j][r];
        }
}

// ---------------------------------------------------------------------------
// a/b projections fused with gating. (unchanged)
// ---------------------------------------------------------------------------
__global__ __launch_bounds__(64) void gating_kernel(
    const float* __restrict__ hs, const float* __restrict__ Wa,
    const float* __restrict__ Wb, const float* __restrict__ A_log,
    const float* __restrict__ dt_bias, float* __restrict__ g,
    float* __restrict__ beta)
{
    const int t = blockIdx.x;
    const int lane = threadIdx.x;
    const float* x = hs + (size_t)t * HIDDEN_D;
    for (int h = 0; h < NUM_VH; ++h) {
        const float* wa = Wa + (size_t)h * HIDDEN_D;
        const float* wb = Wb + (size_t)h * HIDDEN_D;
        float sa = 0.f, sb = 0.f;
        for (int i = lane; i < HIDDEN_D; i += 64) {
            float xv = x[i];
            sa = fmaf(xv, wa[i], sa);
            sb = fmaf(xv, wb[i], sb);
        }
        for (int off = 32; off > 0; off >>= 1) {
            sa += __shfl_down(sa, off);
            sb += __shfl_down(sb, off);
        }
        if (lane == 0) {
            float aa = sa + dt_bias[h];
            float sp = (aa > 20.f) ? aa : log1pf(expf(aa));
            g[t * NUM_VH + h] = -expf(A_log[h]) * sp;
            beta[t * NUM_VH + h] = 1.f / (1.f + expf(-sb));
        }
    }
}

// ---------------------------------------------------------------------------
// Depthwise causal conv1d (K=4) + SiLU. (unchanged)
// ---------------------------------------------------------------------------
__global__ __launch_bounds__(256) void conv_silu_kernel(
    const float* __restrict__ mixed, const float* __restrict__ cw,
    float* __restrict__ qkv)
{
    int idx = blockIdx.x * 256 + threadIdx.x;
    int c = idx & (QKV_TOTAL - 1);
    int t = idx >> 13;
    const float4 w = *(const float4*)(cw + (size_t)c * 4);
    float y = w.w * mixed[(size_t)t * QKV_TOTAL + c];
    if (t >= 1) y = fmaf(w.z, mixed[(size_t)(t - 1) * QKV_TOTAL + c], y);
    if (t >= 2) y = fmaf(w.y, mixed[(size_t)(t - 2) * QKV_TOTAL + c], y);
    if (t >= 3) y = fmaf(w.x, mixed[(size_t)(t - 3) * QKV_TOTAL + c], y);
    qkv[(size_t)t * QKV_TOTAL + c] = y / (1.f + expf(-y));
}

// ---------------------------------------------------------------------------
// L2-normalize q and k head rows in-place. (unchanged)
// ---------------------------------------------------------------------------
__global__ __launch_bounds__(64) void l2norm_kernel(float* __restrict__ qkv)
{
    const int row = blockIdx.x;
    const int t = row >> 5;
    const int r = row & 31;
    float* p = qkv + (size_t)t * QKV_TOTAL + r * HEAD_DIM;
    const int lane = threadIdx.x;
    float2 v = *(float2*)(p + lane * 2);
    float s = v.x * v.x + v.y * v.y;
    for (int off = 32; off > 0; off >>= 1) s += __shfl_down(s, off);
    s = __shfl(s, 0);
    float inv = rsqrtf(s + EPS_F);
    v.x *= inv; v.y *= inv;
    *(float2*)(p + lane * 2) = v;
}

// ---------------------------------------------------------------------------
// GDN phase 1 (fully parallel over 64 chunks x 32 heads):
//   cums_i = prefix(g); W[i][j] = beta_i exp(cum_i-cum_j)(k_i.k_j) (j<i)
//   T = (I+W)^{-1}  (explicit, unit-lower-triangular inversion)
//   Pm[i][j] = exp(cum_i-cum_j)(q~_i.k_j)  for j<=i else 0   (q~ = scale*q)
//   scalars: lam_i = exp(cum_i), beta_i, rlast_i = exp(cum_31-cum_i)
// Outputs: Tbuf/Pbuf [chunk][head][32][32], lam/bet/rl [chunk][head][32].
// ---------------------------------------------------------------------------
__global__ __launch_bounds__(256) void gdn_p1(
    const float* __restrict__ qkv, const float* __restrict__ g,
    const float* __restrict__ beta, float* __restrict__ Tbuf,
    float* __restrict__ Pbuf, float* __restrict__ lam_g,
    float* __restrict__ bet_g, float* __restrict__ rl_g)
{
    __shared__ float Kn[CC][132];
    __shared__ float Qn[CC][132];
    __shared__ float Wm[CC][33];
    __shared__ float Tld[CC][34];
    __shared__ float cums[CC];
    __shared__ float betas[CC];

    const int tid = threadIdx.x;
    const int h   = blockIdx.x;          // 0..31
    const int cix = blockIdx.y;          // 0..63
    const int t0  = cix * CC;
    const int kh  = h >> 1;
    const float scale = 0.08838834764831845f;
    const size_t mb = ((size_t)cix * NUM_VH + h);   // matrix index
    const size_t sb = mb * CC;                      // scalar base

    if (tid < CC) {
        float x = g[(size_t)(t0 + tid) * NUM_VH + h];
        float bv = beta[(size_t)(t0 + tid) * NUM_VH + h];
#pragma unroll
        for (int off = 1; off < 32; off <<= 1) {
            float n = __shfl_up(x, off);
            if (tid >= off) x += n;
        }
        cums[tid] = x;
        betas[tid] = bv;
        float c31 = __shfl(x, 31);
        lam_g[sb + tid] = expf(x);
        bet_g[sb + tid] = bv;
        rl_g[sb + tid]  = expf(c31 - x);
    }
#pragma unroll
    for (int p = 0; p < 4; ++p) {
        int idx = p * 256 + tid;
        int i = idx >> 5, k4 = (idx & 31) * 4;
        const float* qr = qkv + (size_t)(t0 + i) * QKV_TOTAL + kh * HEAD_DIM + k4;
        float4 q4 = *(const float4*)qr;
        float4 k4v = *(const float4*)(qr + K_TOTAL);
        *(float4*)&Kn[i][k4] = k4v;
        q4.x *= scale; q4.y *= scale; q4.z *= scale; q4.w *= scale;
        *(float4*)&Qn[i][k4] = q4;
    }
    __syncthreads();

    // W (lower) and Pm (causal incl. diag)
    {
        const int i0 = (tid >> 4) * 2, j0 = (tid & 15) * 2;
        float wa[2][2] = {{0.f, 0.f}, {0.f, 0.f}};
        float pa[2][2] = {{0.f, 0.f}, {0.f, 0.f}};
        for (int k = 0; k < HEAD_DIM; k += 4) {
            float4 a0 = *(const float4*)&Kn[i0][k];
            float4 a1 = *(const float4*)&Kn[i0 + 1][k];
            float4 b0 = *(const float4*)&Kn[j0][k];
            float4 b1 = *(const float4*)&Kn[j0 + 1][k];
            float4 c0 = *(const float4*)&Qn[i0][k];
            float4 c1 = *(const float4*)&Qn[i0 + 1][k];
            const float* ap0 = (const float*)&a0;
            const float* ap1 = (const float*)&a1;
            const float* bp0 = (const float*)&b0;
            const float* bp1 = (const float*)&b1;
            const float* cp0 = (const float*)&c0;
            const float* cp1 = (const float*)&c1;
#pragma unroll
            for (int cc = 0; cc < 4; ++cc) {
                wa[0][0] = fmaf(ap0[cc], bp0[cc], wa[0][0]);
                wa[0][1] = fmaf(ap0[cc], bp1[cc], wa[0][1]);
                wa[1][0] = fmaf(ap1[cc], bp0[cc], wa[1][0]);
                wa[1][1] = fmaf(ap1[cc], bp1[cc], wa[1][1]);
                pa[0][0] = fmaf(cp0[cc], bp0[cc], pa[0][0]);
                pa[0][1] = fmaf(cp0[cc], bp1[cc], pa[0][1]);
                pa[1][0] = fmaf(cp1[cc], bp0[cc], pa[1][0]);
                pa[1][1] = fmaf(cp1[cc], bp1[cc], pa[1][1]);
            }
        }
        float* Pg = Pbuf + mb * (CC * CC);
#pragma unroll
        for (int di = 0; di < 2; ++di)
#pragma unroll
            for (int dj = 0; dj < 2; ++dj) {
                int i = i0 + di, j = j0 + dj;
                float rr = expf(fminf(cums[i] - cums[j], 0.f));
                Wm[i][j] = (j < i) ? betas[i] * rr * wa[di][dj] : 0.f;
                Pg[i * CC + j] = (j <= i) ? rr * pa[di][dj] : 0.f;
            }
    }
    __syncthreads();

    // invert (I+W): T[i][:] = e_i - sum_{j<i} W[i][j] T[j][:]
    {
        const int col = tid >> 3, tk = tid & 7;
        if (tk == 0) Tld[0][col] = (col == 0) ? 1.f : 0.f;
        for (int i = 1; i < CC; ++i) {
            float part = 0.f;
            for (int j = tk; j < i; j += 8)
                part = fmaf(Wm[i][j], Tld[j][col], part);
            part += __shfl_xor(part, 4);
            part += __shfl_xor(part, 2);
            part += __shfl_xor(part, 1);
            if (tk == 0) Tld[i][col] = ((i == col) ? 1.f : 0.f) - part;
        }
    }
    __syncthreads();
    {
        const int i = tid >> 3, j0 = (tid & 7) * 4;
        float4 t4 = make_float4(Tld[i][j0], Tld[i][j0 + 1],
                                Tld[i][j0 + 2], Tld[i][j0 + 3]);
        *(float4*)(Tbuf + mb * (CC * CC) + tid * 4) = t4;
    }
}

// ---------------------------------------------------------------------------
// GDN phase 2 (sequential over chunks; 256 blocks = 32 heads x 8 v-splits):
// per chunk: R1 = K.S0, R2 = Q~.S0
//            rhs = beta (V - lam R1);  Delta = T rhs
//            O   = lam R2 + Pm Delta
//            S   = lam_31 S + sum_j rlast_j k_j^T Delta_j
// ---------------------------------------------------------------------------
__global__ __launch_bounds__(256) void gdn_p2(
    const float* __restrict__ qkv, const float* __restrict__ Tbuf,
    const float* __restrict__ Pbuf, const float* __restrict__ lam_g,
    const float* __restrict__ bet_g, const float* __restrict__ rl_g,
    float* __restrict__ o)
{
    __shared__ float Kn[CC][132];
    __shared__ float Qn[CC][132];
    __shared__ float Sm[HEAD_DIM][NV + 2];
    __shared__ float Tm[CC][34];
    __shared__ float Pm[CC][34];
    __shared__ float Dl[CC][NV + 2];
    __shared__ float D2[CC][NV + 2];
    __shared__ float lamS[CC], betS[CC], rlS[CC];

    const int tid = threadIdx.x;
    const int h   = blockIdx.x >> 3;
    const int V0  = (blockIdx.x & 7) * NV;
    const int kh  = h >> 1;
    const float scale = 0.08838834764831845f;

    const int ri = tid >> 3;            // 0..31 (row mapping)
    const int rn = (tid & 7) * 2;       // 0..14 (col pair)
    const int fk = (tid >> 3) * 4;      // 0..124 (state-k mapping)

    // zero state
#pragma unroll
    for (int c = 0; c < 4; ++c) {
        Sm[fk + c][rn] = 0.f;
        Sm[fk + c][rn + 1] = 0.f;
    }

    for (int cix = 0; cix < NCHUNK; ++cix) {
        const int t0 = cix * CC;
        const size_t mb = ((size_t)cix * NUM_VH + h);
        __syncthreads();   // protect LDS from previous iteration's readers

        // ---- stage ----
#pragma unroll
        for (int p = 0; p < 4; ++p) {
            int idx = p * 256 + tid;
            int i = idx >> 5, k4 = (idx & 31) * 4;
            const float* qr = qkv + (size_t)(t0 + i) * QKV_TOTAL + kh * HEAD_DIM + k4;
            float4 q4 = *(const float4*)qr;
            float4 k4v = *(const float4*)(qr + K_TOTAL);
            *(float4*)&Kn[i][k4] = k4v;
            q4.x *= scale; q4.y *= scale; q4.z *= scale; q4.w *= scale;
            *(float4*)&Qn[i][k4] = q4;
        }
        {
            float4 t4 = *(const float4*)(Tbuf + mb * (CC * CC) + tid * 4);
            float4 p4 = *(const float4*)(Pbuf + mb * (CC * CC) + tid * 4);
            const int i = tid >> 3, j0 = (tid & 7) * 4;
            Tm[i][j0] = t4.x; Tm[i][j0 + 1] = t4.y;
            Tm[i][j0 + 2] = t4.z; Tm[i][j0 + 3] = t4.w;
            Pm[i][j0] = p4.x; Pm[i][j0 + 1] = p4.y;
            Pm[i][j0 + 2] = p4.z; Pm[i][j0 + 3] = p4.w;
        }
        if (tid < CC) {
            lamS[tid] = lam_g[mb * CC + tid];
            betS[tid] = bet_g[mb * CC + tid];
            rlS[tid]  = rl_g[mb * CC + tid];
        }
        float2 v2 = *(const float2*)(qkv + (size_t)(t0 + ri) * QKV_TOTAL
                                     + 2 * K_TOTAL + h * HEAD_DIM + V0 + rn);
        __syncthreads();

        // ---- R1 = K.S0, R2 = Q~.S0 ; rhs -> Dl ; o1 in regs ----
        float r1x = 0.f, r1y = 0.f, r2x = 0.f, r2y = 0.f;
        for (int k = 0; k < HEAD_DIM; k += 4) {
            float4 kv = *(const float4*)&Kn[ri][k];
            float4 qv = *(const float4*)&Qn[ri][k];
            const float* kp = (const float*)&kv;
            const float* qp = (const float*)&qv;
#pragma unroll
            for (int c4 = 0; c4 < 4; ++c4) {
                float2 s = *(const float2*)&Sm[k + c4][rn];
                r1x = fmaf(kp[c4], s.x, r1x);
                r1y = fmaf(kp[c4], s.y, r1y);
                r2x = fmaf(qp[c4], s.x, r2x);
                r2y = fmaf(qp[c4], s.y, r2y);
            }
        }
        float lam = lamS[ri], bet = betS[ri];
        Dl[ri][rn]     = bet * (v2.x - lam * r1x);
        Dl[ri][rn + 1] = bet * (v2.y - lam * r1y);
        float o1x = lam * r2x, o1y = lam * r2y;
        __syncthreads();

        // ---- Delta = T rhs -> D2 ----
        {
            float dx = 0.f, dy = 0.f;
            for (int j = 0; j < CC; ++j) {
                float t = Tm[ri][j];
                float2 d = *(const float2*)&Dl[j][rn];
                dx = fmaf(t, d.x, dx);
                dy = fmaf(t, d.y, dy);
            }
            D2[ri][rn] = dx; D2[ri][rn + 1] = dy;
        }
        __syncthreads();

        // ---- O = o1 + Pm Delta -> global ----
        {
            float ox = o1x, oy = o1y;
            for (int j = 0; j < CC; ++j) {
                float p = Pm[ri][j];
                float2 d = *(const float2*)&D2[j][rn];
                ox = fmaf(p, d.x, ox);
                oy = fmaf(p, d.y, oy);
            }
            *(float2*)(o + (size_t)(t0 + ri) * V_TOTAL + h * HEAD_DIM + V0 + rn)
                = make_float2(ox, oy);
        }

        // ---- S = lam31 S + sum_j rlast_j k_j^T Delta_j ----
        {
            const float lamL = lamS[CC - 1];
            float s[4][2];
#pragma unroll
            for (int c = 0; c < 4; ++c) {
                s[c][0] = lamL * Sm[fk + c][rn];
                s[c][1] = lamL * Sm[fk + c][rn + 1];
            }
            for (int j = 0; j < CC; ++j) {
                float rl = rlS[j];
                float4 kj = *(const float4*)&Kn[j][fk];
                float2 dj = *(const float2*)&D2[j][rn];
                float rdx = rl * dj.x, rdy = rl * dj.y;
                const float* kp = (const float*)&kj;
#pragma unroll
                for (int c = 0; c < 4; ++c) {
                    s[c][0] = fmaf(kp[c], rdx, s[c][0]);
                    s[c][1] = fmaf(kp[c], rdy, s[c][1]);
                }
            }
#pragma unroll
            for (int c = 0; c < 4; ++c) {
                Sm[fk + c][rn] = s[c][0];
                Sm[fk + c][rn + 1] = s[c][1];
            }
        }
    }
}

// ---------------------------------------------------------------------------
// Gated RMSNorm. (unchanged)
// ---------------------------------------------------------------------------
__global__ __launch_bounds__(64) void rmsnorm_gate_kernel(
    float* __restrict__ o, const float* __restrict__ z,
    const float* __restrict__ nw)
{
    const int row = blockIdx.x;
    float* p = o + (size_t)row * HEAD_DIM;
    const float* zp = z + (size_t)row * HEAD_DIM;
    const int lane = threadIdx.x;
    float2 v = *(float2*)(p + lane * 2);
    float s = v.x * v.x + v.y * v.y;
    for (int off = 32; off > 0; off >>= 1) s += __shfl_down(s, off);
    s = __shfl(s, 0);
    float inv = rsqrtf(s * (1.f / HEAD_DIM) + EPS_F);
    float2 zv = *(float2*)(zp + lane * 2);
    float2 wv = *(const float2*)(nw + lane * 2);
    v.x = v.x * inv * wv.x * (zv.x / (1.f + expf(-zv.x)));
    v.y = v.y * inv * wv.y * (zv.y / (1.f + expf(-zv.y)));
    *(float2*)(p + lane * 2) = v;
}

// ---------------------------------------------------------------------------
extern "C" void kernel_launch(void* const* d_in, const int* in_sizes, int n_in,
                              void* d_out, int out_size, void* d_ws,
                              size_t ws_size, hipStream_t stream)
{
    const float* hs    = (const float*)d_in[0];
    const float* Wqkv  = (const float*)d_in[1];
    const float* Wz    = (const float*)d_in[2];
    const float* Wa    = (const float*)d_in[3];
    const float* Wb    = (const float*)d_in[4];
    const float* cw    = (const float*)d_in[5];
    const float* Wout  = (const float*)d_in[6];
    const float* nw    = (const float*)d_in[7];
    const float* A_log = (const float*)d_in[8];
    const float* dtb   = (const float*)d_in[9];
    float* out = (float*)d_out;

    float* F     = (float*)d_ws;
    float* mixed = F;                          // [0, 16777216) fp32
    float* qkvb  = F + (size_t)16777216;       // [16777216, 33554432)
    float* zb    = F + (size_t)33554432;       // [33554432, 41943040)
    float* gb    = F + (size_t)41943040;
    float* bb    = F + (size_t)42008576;
    float* ob    = mixed;                      // O output: first 8388608 floats

    // p1 outputs live in mixed's upper half (dead after conv, before O write
    // only touches mixed[0..8388608)):
    float* Tbuf  = F + (size_t)8388608;        // 64*32*1024 = 2097152 fl
    float* Pbuf  = F + (size_t)10485760;       // 2097152 fl
    float* lam_b = F + (size_t)12582912;       // 65536 fl
    float* bet_b = F + (size_t)12648448;       // 65536 fl
    float* rl_b  = F + (size_t)12713984;       // 65536 fl

    // bf16 buffers (same dead-region scheme as Round 3)
    unsigned short* hs_bf   = (unsigned short*)(F + (size_t)16777216);
    unsigned short* Wqkv_bf = (unsigned short*)(F + (size_t)18874368);
    unsigned short* Wz_bf   = (unsigned short*)(F + (size_t)27262976);
    unsigned short* ob_bf   = (unsigned short*)(F + (size_t)33554432);
    unsigned short* Wout_bf = (unsigned short*)(F + (size_t)37748736);

    cast_bf16_kernel<<<1048576 / 256, 256, 0, stream>>>(hs, hs_bf, 1048576);
    cast_bf16_kernel<<<4194304 / 256, 256, 0, stream>>>(Wqkv, Wqkv_bf, 4194304);
    cast_bf16_kernel<<<2097152 / 256, 256, 0, stream>>>(Wz, Wz_bf, 2097152);
    gemm_bt_bf16<<<dim3(QKV_TOTAL / 128, T_SEQ / 128), 256, 0, stream>>>(
        hs_bf, Wqkv_bf, mixed, T_SEQ, QKV_TOTAL, HIDDEN_D);
    gemm_bt_bf16<<<dim3(V_TOTAL / 128, T_SEQ / 128), 256, 0, stream>>>(
        hs_bf, Wz_bf, zb, T_SEQ, V_TOTAL, HIDDEN_D);
    gating_kernel<<<T_SEQ, 64, 0, stream>>>(hs, Wa, Wb, A_log, dtb, gb, bb);
    conv_silu_kernel<<<(T_SEQ * QKV_TOTAL) / 256, 256, 0, stream>>>(
        mixed, cw, qkvb);
    l2norm_kernel<<<T_SEQ * 32, 64, 0, stream>>>(qkvb);
    // chunked GDN: parallel phase (T, Pm, scalars), then sequential phase
    gdn_p1<<<dim3(NUM_VH, NCHUNK), 256, 0, stream>>>(
        qkvb, gb, bb, Tbuf, Pbuf, lam_b, bet_b, rl_b);
    gdn_p2<<<NUM_VH * (HEAD_DIM / NV), 256, 0, stream>>>(
        qkvb, Tbuf, Pbuf, lam_b, bet_b, rl_b, ob);
    rmsnorm_gate_kernel<<<T_SEQ * NUM_VH, 64, 0, stream>>>(ob, zb, nw);
    cast_bf16_kernel<<<2097152 / 256, 256, 0, stream>>>(ob, ob_bf, 2097152);
    cast_bf16_kernel<<<2097152 / 256, 256, 0, stream>>>(Wout, Wout_bf, 2097152);
    gemm_bt_bf16<<<dim3(HIDDEN_D / 128, T_SEQ / 128), 256, 0, stream>>>(
        ob_bf, Wout_bf, out, T_SEQ, HIDDEN_D, V_TOTAL);
}

// Round 5
// 979.451 us; speedup vs baseline: 8.5246x; 1.2691x over previous
//
#include <hip/hip_runtime.h>
#include <math.h>

#define T_SEQ     2048
#define HIDDEN_D  2048
#define NUM_KH    16
#define NUM_VH    32
#define HEAD_DIM  128
#define K_TOTAL   2048   // 16*128
#define V_TOTAL   4096   // 32*128
#define QKV_TOTAL 8192   // 2*K_TOTAL + V_TOTAL
#define EPS_F     1e-6f
#define CC        32     // chunk length
#define NCHUNK    (T_SEQ / CC)
#define NV        16     // v-columns per p2 block (Dv split 8 ways)

typedef __attribute__((ext_vector_type(4))) float f32x4;
typedef __attribute__((ext_vector_type(8))) short s16x8;

__device__ __forceinline__ unsigned short f2bf(float f) {
    unsigned int u = __float_as_uint(f);
    u += 0x7FFFu + ((u >> 16) & 1u);   // RNE
    return (unsigned short)(u >> 16);
}

// ---------------------------------------------------------------------------
// fp32 -> bf16 cast.
// ---------------------------------------------------------------------------
__global__ __launch_bounds__(256) void cast_bf16_kernel(
    const float* __restrict__ src, unsigned short* __restrict__ dst, int n4)
{
    int idx = blockIdx.x * 256 + threadIdx.x;
    if (idx >= n4) return;
    float4 v = ((const float4*)src)[idx];
    ushort4 o;
    o.x = f2bf(v.x); o.y = f2bf(v.y); o.z = f2bf(v.z); o.w = f2bf(v.w);
    ((ushort4*)dst)[idx] = o;
}

// ---------------------------------------------------------------------------
// bf16 MFMA GEMM (NT): C[M,N] fp32 = A[M,K]bf16 * B[N,K]bf16^T.
// ---------------------------------------------------------------------------
__global__ __launch_bounds__(256) void gemm_bt_bf16(
    const unsigned short* __restrict__ A, const unsigned short* __restrict__ B,
    float* __restrict__ C, int M, int N, int K)
{
    __shared__ unsigned short As[128 * 64];
    __shared__ unsigned short Bs[128 * 64];
    const int tid  = threadIdx.x;
    const int wave = tid >> 6;
    const int lane = tid & 63;
    const int m0 = blockIdx.y * 128;
    const int n0 = blockIdx.x * 128;
    const int wm = (wave >> 1) * 64;
    const int wn = (wave & 1) * 64;

    f32x4 acc[4][4];
    f32x4 zero = {0.f, 0.f, 0.f, 0.f};
#pragma unroll
    for (int i = 0; i < 4; ++i)
#pragma unroll
        for (int j = 0; j < 4; ++j) acc[i][j] = zero;

    const int srow = lane >> 3;
    const int scol = (lane & 7) * 8;
    const int rm = lane & 15;
    const int koq = (lane >> 4) * 8;

    for (int kt = 0; kt < K; kt += 64) {
#pragma unroll
        for (int l = 0; l < 4; ++l) {
            const int r0 = wave * 32 + l * 8;
            const unsigned short* ga =
                A + (size_t)(m0 + r0 + srow) * K + kt + scol;
            const unsigned short* gb =
                B + (size_t)(n0 + r0 + srow) * K + kt + scol;
            __builtin_amdgcn_global_load_lds(
                (const __attribute__((address_space(1))) void*)ga,
                (__attribute__((address_space(3))) void*)&As[r0 * 64], 16, 0, 0);
            __builtin_amdgcn_global_load_lds(
                (const __attribute__((address_space(1))) void*)gb,
                (__attribute__((address_space(3))) void*)&Bs[r0 * 64], 16, 0, 0);
        }
        __syncthreads();

#pragma unroll
        for (int ks = 0; ks < 2; ++ks) {
            const int ko = ks * 32 + koq;
            s16x8 af[4], bfr[4];
#pragma unroll
            for (int i = 0; i < 4; ++i) {
                af[i]  = *(const s16x8*)&As[(wm + i * 16 + rm) * 64 + ko];
                bfr[i] = *(const s16x8*)&Bs[(wn + i * 16 + rm) * 64 + ko];
            }
#pragma unroll
            for (int i = 0; i < 4; ++i)
#pragma unroll
                for (int j = 0; j < 4; ++j)
                    acc[i][j] = __builtin_amdgcn_mfma_f32_16x16x32_bf16(
                        af[i], bfr[j], acc[i][j], 0, 0, 0);
        }
        __syncthreads();
    }

    const int cr = (lane >> 4) * 4;
    const int ccol = lane & 15;
#pragma unroll
    for (int i = 0; i < 4; ++i)
#pragma unroll
        for (int j = 0; j < 4; ++j) {
#pragma unroll
            for (int r = 0; r < 4; ++r)
                C[(size_t)(m0 + wm + i * 16 + cr + r) * N
                  + n0 + wn + j * 16 + ccol] = acc[i][j][r];
        }
}

// ---------------------------------------------------------------------------
// fp32 tile GEMM (NT), used for the small ab projection (N=64).
// C[M,N] = A[M,K] * B[N,K]^T.  64x64 tile, BK=16, 256 threads, 4x4 microtile.
// ---------------------------------------------------------------------------
__global__ __launch_bounds__(256) void gemm_nt_64(
    const float* __restrict__ A, const float* __restrict__ B,
    float* __restrict__ C, int M, int N, int K)
{
    __shared__ float As[16][68];
    __shared__ float Bs[16][68];
    const int tid = threadIdx.x;
    const int m0 = blockIdx.y * 64;
    const int n0 = blockIdx.x * 64;
    const int tm = tid >> 4;
    const int tn = tid & 15;
    const int lr = tid >> 2;
    const int lc = (tid & 3) * 4;

    float acc[4][4];
#pragma unroll
    for (int i = 0; i < 4; ++i)
#pragma unroll
        for (int j = 0; j < 4; ++j) acc[i][j] = 0.f;

    for (int kt = 0; kt < K; kt += 16) {
        float4 av = *(const float4*)(A + (size_t)(m0 + lr) * K + kt + lc);
        float4 bv = *(const float4*)(B + (size_t)(n0 + lr) * K + kt + lc);
        As[lc + 0][lr] = av.x; As[lc + 1][lr] = av.y;
        As[lc + 2][lr] = av.z; As[lc + 3][lr] = av.w;
        Bs[lc + 0][lr] = bv.x; Bs[lc + 1][lr] = bv.y;
        Bs[lc + 2][lr] = bv.z; Bs[lc + 3][lr] = bv.w;
        __syncthreads();
#pragma unroll
        for (int kk = 0; kk < 16; ++kk) {
            float4 a4 = *(const float4*)&As[kk][tm * 4];
            float4 b4 = *(const float4*)&Bs[kk][tn * 4];
            float a[4] = {a4.x, a4.y, a4.z, a4.w};
            float b[4] = {b4.x, b4.y, b4.z, b4.w};
#pragma unroll
            for (int i = 0; i < 4; ++i)
#pragma unroll
                for (int j = 0; j < 4; ++j)
                    acc[i][j] = fmaf(a[i], b[j], acc[i][j]);
        }
        __syncthreads();
    }
#pragma unroll
    for (int i = 0; i < 4; ++i) {
        float4 o = make_float4(acc[i][0], acc[i][1], acc[i][2], acc[i][3]);
        *(float4*)(C + (size_t)(m0 + tm * 4 + i) * N + n0 + tn * 4) = o;
    }
}

// ---------------------------------------------------------------------------
// Concat Wa (32x2048) and Wb (32x2048) into Wab (64x2048), float4 copies.
// ---------------------------------------------------------------------------
__global__ __launch_bounds__(256) void concat_ab_kernel(
    const float* __restrict__ Wa, const float* __restrict__ Wb,
    float* __restrict__ Wab)
{
    int idx = blockIdx.x * 256 + threadIdx.x;          // float4 index, 32768
    int half = 16384;                                  // 32*2048/4
    const float* src = (idx < half) ? Wa : Wb;
    int off = (idx < half) ? idx : idx - half;
    ((float4*)Wab)[idx] = ((const float4*)src)[off];
}

// ---------------------------------------------------------------------------
// Gating finalize: from ab[T,64] (a in cols 0..31, b in cols 32..63) compute
// g = -exp(A_log)*softplus(a+dt_bias), beta = sigmoid(b).
// ---------------------------------------------------------------------------
__global__ __launch_bounds__(256) void gating_finalize_kernel(
    const float* __restrict__ ab, const float* __restrict__ A_log,
    const float* __restrict__ dt_bias, float* __restrict__ g,
    float* __restrict__ beta)
{
    int idx = blockIdx.x * 256 + threadIdx.x;          // t*32 + h
    int t = idx >> 5, h = idx & 31;
    float a = ab[t * 64 + h] + dt_bias[h];
    float b = ab[t * 64 + 32 + h];
    float sp = (a > 20.f) ? a : log1pf(expf(a));
    g[idx] = -expf(A_log[h]) * sp;
    beta[idx] = 1.f / (1.f + expf(-b));
}

// ---------------------------------------------------------------------------
// Depthwise causal conv1d (K=4) + SiLU.
// ---------------------------------------------------------------------------
__global__ __launch_bounds__(256) void conv_silu_kernel(
    const float* __restrict__ mixed, const float* __restrict__ cw,
    float* __restrict__ qkv)
{
    int idx = blockIdx.x * 256 + threadIdx.x;
    int c = idx & (QKV_TOTAL - 1);
    int t = idx >> 13;
    const float4 w = *(const float4*)(cw + (size_t)c * 4);
    float y = w.w * mixed[(size_t)t * QKV_TOTAL + c];
    if (t >= 1) y = fmaf(w.z, mixed[(size_t)(t - 1) * QKV_TOTAL + c], y);
    if (t >= 2) y = fmaf(w.y, mixed[(size_t)(t - 2) * QKV_TOTAL + c], y);
    if (t >= 3) y = fmaf(w.x, mixed[(size_t)(t - 3) * QKV_TOTAL + c], y);
    qkv[(size_t)t * QKV_TOTAL + c] = y / (1.f + expf(-y));
}

// ---------------------------------------------------------------------------
// L2-normalize q and k head rows in-place.
// ---------------------------------------------------------------------------
__global__ __launch_bounds__(64) void l2norm_kernel(float* __restrict__ qkv)
{
    const int row = blockIdx.x;
    const int t = row >> 5;
    const int r = row & 31;
    float* p = qkv + (size_t)t * QKV_TOTAL + r * HEAD_DIM;
    const int lane = threadIdx.x;
    float2 v = *(float2*)(p + lane * 2);
    float s = v.x * v.x + v.y * v.y;
    for (int off = 32; off > 0; off >>= 1) s += __shfl_down(s, off);
    s = __shfl(s, 0);
    float inv = rsqrtf(s + EPS_F);
    v.x *= inv; v.y *= inv;
    *(float2*)(p + lane * 2) = v;
}

// ---------------------------------------------------------------------------
// GDN phase 1 (fully parallel over 64 chunks x 32 heads): T=(I+W)^-1, Pm,
// per-row scalars.  (unchanged from Round 4)
// ---------------------------------------------------------------------------
__global__ __launch_bounds__(256) void gdn_p1(
    const float* __restrict__ qkv, const float* __restrict__ g,
    const float* __restrict__ beta, float* __restrict__ Tbuf,
    float* __restrict__ Pbuf, float* __restrict__ lam_g,
    float* __restrict__ bet_g, float* __restrict__ rl_g)
{
    __shared__ float Kn[CC][132];
    __shared__ float Qn[CC][132];
    __shared__ float Wm[CC][33];
    __shared__ float Tld[CC][34];
    __shared__ float cums[CC];
    __shared__ float betas[CC];

    const int tid = threadIdx.x;
    const int h   = blockIdx.x;
    const int cix = blockIdx.y;
    const int t0  = cix * CC;
    const int kh  = h >> 1;
    const float scale = 0.08838834764831845f;
    const size_t mb = ((size_t)cix * NUM_VH + h);
    const size_t sb = mb * CC;

    if (tid < CC) {
        float x = g[(size_t)(t0 + tid) * NUM_VH + h];
        float bv = beta[(size_t)(t0 + tid) * NUM_VH + h];
#pragma unroll
        for (int off = 1; off < 32; off <<= 1) {
            float n = __shfl_up(x, off);
            if (tid >= off) x += n;
        }
        cums[tid] = x;
        betas[tid] = bv;
        float c31 = __shfl(x, 31);
        lam_g[sb + tid] = expf(x);
        bet_g[sb + tid] = bv;
        rl_g[sb + tid]  = expf(c31 - x);
    }
#pragma unroll
    for (int p = 0; p < 4; ++p) {
        int idx = p * 256 + tid;
        int i = idx >> 5, k4 = (idx & 31) * 4;
        const float* qr = qkv + (size_t)(t0 + i) * QKV_TOTAL + kh * HEAD_DIM + k4;
        float4 q4 = *(const float4*)qr;
        float4 k4v = *(const float4*)(qr + K_TOTAL);
        *(float4*)&Kn[i][k4] = k4v;
        q4.x *= scale; q4.y *= scale; q4.z *= scale; q4.w *= scale;
        *(float4*)&Qn[i][k4] = q4;
    }
    __syncthreads();

    {
        const int i0 = (tid >> 4) * 2, j0 = (tid & 15) * 2;
        float wa[2][2] = {{0.f, 0.f}, {0.f, 0.f}};
        float pa[2][2] = {{0.f, 0.f}, {0.f, 0.f}};
        for (int k = 0; k < HEAD_DIM; k += 4) {
            float4 a0 = *(const float4*)&Kn[i0][k];
            float4 a1 = *(const float4*)&Kn[i0 + 1][k];
            float4 b0 = *(const float4*)&Kn[j0][k];
            float4 b1 = *(const float4*)&Kn[j0 + 1][k];
            float4 c0 = *(const float4*)&Qn[i0][k];
            float4 c1 = *(const float4*)&Qn[i0 + 1][k];
            const float* ap0 = (const float*)&a0;
            const float* ap1 = (const float*)&a1;
            const float* bp0 = (const float*)&b0;
            const float* bp1 = (const float*)&b1;
            const float* cp0 = (const float*)&c0;
            const float* cp1 = (const float*)&c1;
#pragma unroll
            for (int cc = 0; cc < 4; ++cc) {
                wa[0][0] = fmaf(ap0[cc], bp0[cc], wa[0][0]);
                wa[0][1] = fmaf(ap0[cc], bp1[cc], wa[0][1]);
                wa[1][0] = fmaf(ap1[cc], bp0[cc], wa[1][0]);
                wa[1][1] = fmaf(ap1[cc], bp1[cc], wa[1][1]);
                pa[0][0] = fmaf(cp0[cc], bp0[cc], pa[0][0]);
                pa[0][1] = fmaf(cp0[cc], bp1[cc], pa[0][1]);
                pa[1][0] = fmaf(cp1[cc], bp0[cc], pa[1][0]);
                pa[1][1] = fmaf(cp1[cc], bp1[cc], pa[1][1]);
            }
        }
        float* Pg = Pbuf + mb * (CC * CC);
#pragma unroll
        for (int di = 0; di < 2; ++di)
#pragma unroll
            for (int dj = 0; dj < 2; ++dj) {
                int i = i0 + di, j = j0 + dj;
                float rr = expf(fminf(cums[i] - cums[j], 0.f));
                Wm[i][j] = (j < i) ? betas[i] * rr * wa[di][dj] : 0.f;
                Pg[i * CC + j] = (j <= i) ? rr * pa[di][dj] : 0.f;
            }
    }
    __syncthreads();

    {
        const int col = tid >> 3, tk = tid & 7;
        if (tk == 0) Tld[0][col] = (col == 0) ? 1.f : 0.f;
        for (int i = 1; i < CC; ++i) {
            float part = 0.f;
            for (int j = tk; j < i; j += 8)
                part = fmaf(Wm[i][j], Tld[j][col], part);
            part += __shfl_xor(part, 4);
            part += __shfl_xor(part, 2);
            part += __shfl_xor(part, 1);
            if (tk == 0) Tld[i][col] = ((i == col) ? 1.f : 0.f) - part;
        }
    }
    __syncthreads();
    {
        const int i = tid >> 3, j0 = (tid & 7) * 4;
        float4 t4 = make_float4(Tld[i][j0], Tld[i][j0 + 1],
                                Tld[i][j0 + 2], Tld[i][j0 + 3]);
        *(float4*)(Tbuf + mb * (CC * CC) + tid * 4) = t4;
    }
}

// ---------------------------------------------------------------------------
// GDN phase 2 (sequential over chunks; 256 blocks).  (unchanged from Round 4)
// ---------------------------------------------------------------------------
__global__ __launch_bounds__(256) void gdn_p2(
    const float* __restrict__ qkv, const float* __restrict__ Tbuf,
    const float* __restrict__ Pbuf, const float* __restrict__ lam_g,
    const float* __restrict__ bet_g, const float* __restrict__ rl_g,
    float* __restrict__ o)
{
    __shared__ float Kn[CC][132];
    __shared__ float Qn[CC][132];
    __shared__ float Sm[HEAD_DIM][NV + 2];
    __shared__ float Tm[CC][34];
    __shared__ float Pm[CC][34];
    __shared__ float Dl[CC][NV + 2];
    __shared__ float D2[CC][NV + 2];
    __shared__ float lamS[CC], betS[CC], rlS[CC];

    const int tid = threadIdx.x;
    const int h   = blockIdx.x >> 3;
    const int V0  = (blockIdx.x & 7) * NV;
    const int kh  = h >> 1;
    const float scale = 0.08838834764831845f;

    const int ri = tid >> 3;
    const int rn = (tid & 7) * 2;
    const int fk = (tid >> 3) * 4;

#pragma unroll
    for (int c = 0; c < 4; ++c) {
        Sm[fk + c][rn] = 0.f;
        Sm[fk + c][rn + 1] = 0.f;
    }

    for (int cix = 0; cix < NCHUNK; ++cix) {
        const int t0 = cix * CC;
        const size_t mb = ((size_t)cix * NUM_VH + h);
        __syncthreads();

#pragma unroll
        for (int p = 0; p < 4; ++p) {
            int idx = p * 256 + tid;
            int i = idx >> 5, k4 = (idx & 31) * 4;
            const float* qr = qkv + (size_t)(t0 + i) * QKV_TOTAL + kh * HEAD_DIM + k4;
            float4 q4 = *(const float4*)qr;
            float4 k4v = *(const float4*)(qr + K_TOTAL);
            *(float4*)&Kn[i][k4] = k4v;
            q4.x *= scale; q4.y *= scale; q4.z *= scale; q4.w *= scale;
            *(float4*)&Qn[i][k4] = q4;
        }
        {
            float4 t4 = *(const float4*)(Tbuf + mb * (CC * CC) + tid * 4);
            float4 p4 = *(const float4*)(Pbuf + mb * (CC * CC) + tid * 4);
            const int i = tid >> 3, j0 = (tid & 7) * 4;
            Tm[i][j0] = t4.x; Tm[i][j0 + 1] = t4.y;
            Tm[i][j0 + 2] = t4.z; Tm[i][j0 + 3] = t4.w;
            Pm[i][j0] = p4.x; Pm[i][j0 + 1] = p4.y;
            Pm[i][j0 + 2] = p4.z; Pm[i][j0 + 3] = p4.w;
        }
        if (tid < CC) {
            lamS[tid] = lam_g[mb * CC + tid];
            betS[tid] = bet_g[mb * CC + tid];
            rlS[tid]  = rl_g[mb * CC + tid];
        }
        float2 v2 = *(const float2*)(qkv + (size_t)(t0 + ri) * QKV_TOTAL
                                     + 2 * K_TOTAL + h * HEAD_DIM + V0 + rn);
        __syncthreads();

        float r1x = 0.f, r1y = 0.f, r2x = 0.f, r2y = 0.f;
        for (int k = 0; k < HEAD_DIM; k += 4) {
            float4 kv = *(const float4*)&Kn[ri][k];
            float4 qv = *(const float4*)&Qn[ri][k];
            const float* kp = (const float*)&kv;
            const float* qp = (const float*)&qv;
#pragma unroll
            for (int c4 = 0; c4 < 4; ++c4) {
                float2 s = *(const float2*)&Sm[k + c4][rn];
                r1x = fmaf(kp[c4], s.x, r1x);
                r1y = fmaf(kp[c4], s.y, r1y);
                r2x = fmaf(qp[c4], s.x, r2x);
                r2y = fmaf(qp[c4], s.y, r2y);
            }
        }
        float lam = lamS[ri], bet = betS[ri];
        Dl[ri][rn]     = bet * (v2.x - lam * r1x);
        Dl[ri][rn + 1] = bet * (v2.y - lam * r1y);
        float o1x = lam * r2x, o1y = lam * r2y;
        __syncthreads();

        {
            float dx = 0.f, dy = 0.f;
            for (int j = 0; j < CC; ++j) {
                float t = Tm[ri][j];
                float2 d = *(const float2*)&Dl[j][rn];
                dx = fmaf(t, d.x, dx);
                dy = fmaf(t, d.y, dy);
            }
            D2[ri][rn] = dx; D2[ri][rn + 1] = dy;
        }
        __syncthreads();

        {
            float ox = o1x, oy = o1y;
            for (int j = 0; j < CC; ++j) {
                float p = Pm[ri][j];
                float2 d = *(const float2*)&D2[j][rn];
                ox = fmaf(p, d.x, ox);
                oy = fmaf(p, d.y, oy);
            }
            *(float2*)(o + (size_t)(t0 + ri) * V_TOTAL + h * HEAD_DIM + V0 + rn)
                = make_float2(ox, oy);
        }

        {
            const float lamL = lamS[CC - 1];
            float s[4][2];
#pragma unroll
            for (int c = 0; c < 4; ++c) {
                s[c][0] = lamL * Sm[fk + c][rn];
                s[c][1] = lamL * Sm[fk + c][rn + 1];
            }
            for (int j = 0; j < CC; ++j) {
                float rl = rlS[j];
                float4 kj = *(const float4*)&Kn[j][fk];
                float2 dj = *(const float2*)&D2[j][rn];
                float rdx = rl * dj.x, rdy = rl * dj.y;
                const float* kp = (const float*)&kj;
#pragma unroll
                for (int c = 0; c < 4; ++c) {
                    s[c][0] = fmaf(kp[c], rdx, s[c][0]);
                    s[c][1] = fmaf(kp[c], rdy, s[c][1]);
                }
            }
#pragma unroll
            for (int c = 0; c < 4; ++c) {
                Sm[fk + c][rn] = s[c][0];
                Sm[fk + c][rn + 1] = s[c][1];
            }
        }
    }
}

// ---------------------------------------------------------------------------
// Gated RMSNorm.
// ---------------------------------------------------------------------------
__global__ __launch_bounds__(64) void rmsnorm_gate_kernel(
    float* __restrict__ o, const float* __restrict__ z,
    const float* __restrict__ nw)
{
    const int row = blockIdx.x;
    float* p = o + (size_t)row * HEAD_DIM;
    const float* zp = z + (size_t)row * HEAD_DIM;
    const int lane = threadIdx.x;
    float2 v = *(float2*)(p + lane * 2);
    float s = v.x * v.x + v.y * v.y;
    for (int off = 32; off > 0; off >>= 1) s += __shfl_down(s, off);
    s = __shfl(s, 0);
    float inv = rsqrtf(s * (1.f / HEAD_DIM) + EPS_F);
    float2 zv = *(float2*)(zp + lane * 2);
    float2 wv = *(const float2*)(nw + lane * 2);
    v.x = v.x * inv * wv.x * (zv.x / (1.f + expf(-zv.x)));
    v.y = v.y * inv * wv.y * (zv.y / (1.f + expf(-zv.y)));
    *(float2*)(p + lane * 2) = v;
}

// ---------------------------------------------------------------------------
extern "C" void kernel_launch(void* const* d_in, const int* in_sizes, int n_in,
                              void* d_out, int out_size, void* d_ws,
                              size_t ws_size, hipStream_t stream)
{
    const float* hs    = (const float*)d_in[0];
    const float* Wqkv  = (const float*)d_in[1];
    const float* Wz    = (const float*)d_in[2];
    const float* Wa    = (const float*)d_in[3];
    const float* Wb    = (const float*)d_in[4];
    const float* cw    = (const float*)d_in[5];
    const float* Wout  = (const float*)d_in[6];
    const float* nw    = (const float*)d_in[7];
    const float* A_log = (const float*)d_in[8];
    const float* dtb   = (const float*)d_in[9];
    float* out = (float*)d_out;

    float* F     = (float*)d_ws;
    float* mixed = F;                          // [0, 16777216) fp32
    float* qkvb  = F + (size_t)16777216;       // [16777216, 33554432)
    float* zb    = F + (size_t)33554432;       // [33554432, 41943040)
    float* gb    = F + (size_t)41943040;
    float* bb    = F + (size_t)42008576;
    float* ob    = mixed;                      // O output: first 8388608 floats

    // p1 outputs in mixed's upper half (dead after conv):
    float* Tbuf  = F + (size_t)8388608;
    float* Pbuf  = F + (size_t)10485760;
    float* lam_b = F + (size_t)12582912;
    float* bet_b = F + (size_t)12648448;
    float* rl_b  = F + (size_t)12713984;

    // bf16 buffers in dead fp32 regions:
    unsigned short* hs_bf   = (unsigned short*)(F + (size_t)16777216);
    unsigned short* Wqkv_bf = (unsigned short*)(F + (size_t)18874368);
    unsigned short* Wz_bf   = (unsigned short*)(F + (size_t)27262976);
    unsigned short* ob_bf   = (unsigned short*)(F + (size_t)33554432);
    unsigned short* Wout_bf = (unsigned short*)(F + (size_t)37748736);

    // gating scratch lives in the ex-Wz_bf region (dead after z-GEMM, before
    // conv overwrites qkvb):
    float* Wab = F + (size_t)27262976;         // 64*2048   = 131072 fl
    float* ab  = F + (size_t)27394048;         // 2048*64   = 131072 fl

    cast_bf16_kernel<<<1048576 / 256, 256, 0, stream>>>(hs, hs_bf, 1048576);
    cast_bf16_kernel<<<4194304 / 256, 256, 0, stream>>>(Wqkv, Wqkv_bf, 4194304);
    cast_bf16_kernel<<<2097152 / 256, 256, 0, stream>>>(Wz, Wz_bf, 2097152);
    gemm_bt_bf16<<<dim3(QKV_TOTAL / 128, T_SEQ / 128), 256, 0, stream>>>(
        hs_bf, Wqkv_bf, mixed, T_SEQ, QKV_TOTAL, HIDDEN_D);
    gemm_bt_bf16<<<dim3(V_TOTAL / 128, T_SEQ / 128), 256, 0, stream>>>(
        hs_bf, Wz_bf, zb, T_SEQ, V_TOTAL, HIDDEN_D);
    // gating as GEMM: Wab = [Wa;Wb], ab = hs @ Wab^T (fp32), then pointwise
    concat_ab_kernel<<<32768 / 256, 256, 0, stream>>>(Wa, Wb, Wab);
    gemm_nt_64<<<dim3(1, T_SEQ / 64), 256, 0, stream>>>(
        hs, Wab, ab, T_SEQ, 64, HIDDEN_D);
    gating_finalize_kernel<<<(T_SEQ * NUM_VH) / 256, 256, 0, stream>>>(
        ab, A_log, dtb, gb, bb);
    conv_silu_kernel<<<(T_SEQ * QKV_TOTAL) / 256, 256, 0, stream>>>(
        mixed, cw, qkvb);
    l2norm_kernel<<<T_SEQ * 32, 64, 0, stream>>>(qkvb);
    gdn_p1<<<dim3(NUM_VH, NCHUNK), 256, 0, stream>>>(
        qkvb, gb, bb, Tbuf, Pbuf, lam_b, bet_b, rl_b);
    gdn_p2<<<NUM_VH * (HEAD_DIM / NV), 256, 0, stream>>>(
        qkvb, Tbuf, Pbuf, lam_b, bet_b, rl_b, ob);
    rmsnorm_gate_kernel<<<T_SEQ * NUM_VH, 64, 0, stream>>>(ob, zb, nw);
    cast_bf16_kernel<<<2097152 / 256, 256, 0, stream>>>(ob, ob_bf, 2097152);
    cast_bf16_kernel<<<2097152 / 256, 256, 0, stream>>>(Wout, Wout_bf, 2097152);
    gemm_bt_bf16<<<dim3(HIDDEN_D / 128, T_SEQ / 128), 256, 0, stream>>>(
        ob_bf, Wout_bf, out, T_SEQ, HIDDEN_D, V_TOTAL);
}